// Round 1
// baseline (3893.713 us; speedup 1.0000x reference)
//
#include <hip/hip_runtime.h>
#include <hip/hip_bf16.h>

#define NH 96
#define NW 96
#define NB 8
#define CIN 192
#define COUT 768   // 4 heads * 3 * 64
#define HD 64

typedef __attribute__((ext_vector_type(8))) unsigned short ushort8;

static __device__ __forceinline__ unsigned short f2bf(float f) {
    unsigned int u = __float_as_uint(f);
    unsigned int r = (u + 0x7fffu + ((u >> 16) & 1u)) >> 16;
    return (unsigned short)r;
}
static __device__ __forceinline__ float bf2f(unsigned short us) {
    return __uint_as_float(((unsigned int)us) << 16);
}

// ---- 3x3 SAME conv, NCHW fp32 in -> NHWC bf16 out (+bias) ----
// block: 256 threads = 16x16 spatial tile; 32 output channels per thread.
__global__ __launch_bounds__(256) void conv_qkv_kernel(
    const float* __restrict__ x, const float* __restrict__ w,
    const float* __restrict__ b, unsigned short* __restrict__ qkv)
{
    __shared__ float xs[18][18];
    int bid = blockIdx.x;
    int cg   = bid % 24;             // c_out group (32 each)
    int tile = (bid / 24) % 36;      // 6x6 tiles of 16x16
    int n    = bid / (24 * 36);
    int tx0 = (tile % 6) * 16;
    int ty0 = (tile / 6) * 16;
    int c0 = cg * 32;
    int tid = threadIdx.x;
    int tx = tid & 15, ty = tid >> 4;

    float acc[32];
#pragma unroll
    for (int i = 0; i < 32; ++i) acc[i] = 0.f;

    for (int ci = 0; ci < CIN; ++ci) {
        // stage 18x18 input tile (halo 1) for channel ci
        for (int t = tid; t < 324; t += 256) {
            int ly = t / 18, lx = t % 18;
            int gy = ty0 + ly - 1, gx = tx0 + lx - 1;
            float v = 0.f;
            if (gy >= 0 && gy < NH && gx >= 0 && gx < NW)
                v = x[(((size_t)n * CIN + ci) * NH + gy) * NW + gx];
            xs[ly][lx] = v;
        }
        __syncthreads();
        float xv[3][3];
#pragma unroll
        for (int di = 0; di < 3; ++di)
#pragma unroll
            for (int dj = 0; dj < 3; ++dj)
                xv[di][dj] = xs[ty + di][tx + dj];
        const float* wp = w + ((size_t)c0 * CIN + ci) * 9;
#pragma unroll
        for (int co = 0; co < 32; ++co) {
            const float* wc = wp + (size_t)co * CIN * 9;  // uniform -> s_load
            float a = acc[co];
#pragma unroll
            for (int k = 0; k < 9; ++k)
                a = fmaf(wc[k], xv[k / 3][k % 3], a);
            acc[co] = a;
        }
        __syncthreads();
    }

    int y = ty0 + ty, xg = tx0 + tx;
    size_t base = (((size_t)n * NH + y) * NW + xg) * COUT + c0;
#pragma unroll
    for (int v8 = 0; v8 < 4; ++v8) {
        ushort8 pk;
#pragma unroll
        for (int j = 0; j < 8; ++j) {
            float val = acc[v8 * 8 + j] + b[c0 + v8 * 8 + j];
            pk[j] = f2bf(val);
        }
        *reinterpret_cast<ushort8*>(qkv + base + v8 * 8) = pk;
    }
}

// ---- neighborhood attention: one wave per (pixel, head), lane = dim ----
template<int KS>
__global__ __launch_bounds__(256) void na_kernel(
    const unsigned short* __restrict__ qkv, float* __restrict__ out, int head)
{
    constexpr int PAD = KS / 2;
    __shared__ float sout[4][65];
    int bid = blockIdx.x;
    int xg = bid % 24;               // group of 4 x-pixels
    int y  = (bid / 24) % NH;
    int n  = bid / (24 * NH);
    int lane = threadIdx.x & 63;
    int wv   = threadIdx.x >> 6;
    int x = xg * 4 + wv;

    size_t pixbase = (((size_t)n * NH + y) * NW + x) * COUT + (size_t)head * 192;
    float q = bf2f(qkv[pixbase + lane]) * 0.125f;   // 1/sqrt(64)

    float m = -1e30f, l = 0.f, acc = 0.f;
    for (int di = 0; di < KS; ++di) {
        int iy = y + di - PAD;
        if (iy < 0 || iy >= NH) continue;
        for (int dj = 0; dj < KS; ++dj) {
            int ix = x + dj - PAD;
            if (ix < 0 || ix >= NW) continue;
            size_t nb = (((size_t)n * NH + iy) * NW + ix) * COUT + (size_t)head * 192;
            float kv = bf2f(qkv[nb + 64 + lane]);
            float t = q * kv;
#pragma unroll
            for (int off = 32; off >= 1; off >>= 1)
                t += __shfl_xor(t, off, 64);
            float s = t;                       // uniform across lanes
            if (s > m) {
                float r = __expf(m - s);
                l *= r; acc *= r; m = s;
            }
            float p = __expf(s - m);
            float vv = bf2f(qkv[nb + 128 + lane]);
            l += p;
            acc = fmaf(p, vv, acc);
        }
    }
    sout[wv][lane] = acc / l;
    __syncthreads();
    int d = threadIdx.x >> 2, xi = threadIdx.x & 3;
    float val = sout[xi][d];
    size_t o = (size_t)head * 4718592 + (size_t)n * 589824 +
               (size_t)d * 9216 + (size_t)y * 96 + (size_t)(xg * 4 + xi);
    out[o] = val;
}

extern "C" void kernel_launch(void* const* d_in, const int* in_sizes, int n_in,
                              void* d_out, int out_size, void* d_ws, size_t ws_size,
                              hipStream_t stream) {
    const float* x  = (const float*)d_in[0];
    const float* w  = (const float*)d_in[1];
    const float* b  = (const float*)d_in[2];
    float* out = (float*)d_out;
    unsigned short* qkv = (unsigned short*)d_ws;  // NHWC bf16, 8*96*96*768

    conv_qkv_kernel<<<NB * 36 * 24, 256, 0, stream>>>(x, w, b, qkv);

    const int na_grid = (NW / 4) * NH * NB;  // 18432
    na_kernel<3><<<na_grid, 256, 0, stream>>>(qkv, out, 0);
    na_kernel<5><<<na_grid, 256, 0, stream>>>(qkv, out, 1);
    na_kernel<7><<<na_grid, 256, 0, stream>>>(qkv, out, 2);
    na_kernel<9><<<na_grid, 256, 0, stream>>>(qkv, out, 3);
}

// Round 2
// 1152.320 us; speedup vs baseline: 3.3790x; 3.3790x over previous
//
#include <hip/hip_runtime.h>
#include <hip/hip_bf16.h>

#define NH 96
#define NW 96
#define NB 8
#define CIN 192
#define COUT 768   // 4 heads * 3 * 64
#define PH 98      // padded spatial dim

typedef __attribute__((ext_vector_type(8))) unsigned short ushort8;
typedef __attribute__((ext_vector_type(8))) short bf16x8;
typedef __attribute__((ext_vector_type(4))) float f32x4;

static __device__ __forceinline__ unsigned short f2bf(float f) {
    unsigned int u = __float_as_uint(f);
    return (unsigned short)((u + 0x7fffu + ((u >> 16) & 1u)) >> 16);
}
static __device__ __forceinline__ float bf2f(unsigned short us) {
    return __uint_as_float(((unsigned int)us) << 16);
}

typedef const __attribute__((address_space(1))) unsigned int gu32;
typedef __attribute__((address_space(3))) unsigned int lu32;
static __device__ __forceinline__ void gload16(const void* g, void* l) {
    __builtin_amdgcn_global_load_lds((gu32*)g, (lu32*)l, 16, 0, 0);
}

// ---- pack x: NCHW fp32 -> zero-padded NHWC bf16 [8][98][98][192] ----
__global__ __launch_bounds__(256) void pack_x_kernel(
    const float* __restrict__ x, unsigned short* __restrict__ xp)
{
    __shared__ float tile[32][97];
    int bid = blockIdx.x;
    int ct = bid % 6; int y = (bid / 6) % NH; int n = bid / (6 * NH);
    int tid = threadIdx.x;
    int c0 = ct * 32;
    for (int i = tid; i < 32 * 96; i += 256) {
        int c = i / 96, xx = i % 96;
        tile[c][xx] = x[(((size_t)n * CIN + c0 + c) * NH + y) * NW + xx];
    }
    __syncthreads();
    for (int i = tid; i < 96 * 4; i += 256) {
        int xx = i >> 2, ch = i & 3;
        ushort8 pk;
#pragma unroll
        for (int j = 0; j < 8; ++j) pk[j] = f2bf(tile[ch * 8 + j][xx]);
        *(ushort8*)(xp + ((size_t)(n * PH + y + 1) * PH + xx + 1) * CIN + c0 + ch * 8) = pk;
    }
}

// ---- pack w: [co][ci][3][3] fp32 -> [co][(di*3+dj)*192+ci] bf16 ----
__global__ __launch_bounds__(256) void pack_w_kernel(
    const float* __restrict__ w, unsigned short* __restrict__ bw)
{
    __shared__ float ls[1728];
    int co = blockIdx.x; int tid = threadIdx.x;
    for (int i = tid; i < 1728; i += 256) ls[i] = w[(size_t)co * 1728 + i];
    __syncthreads();
    for (int i = tid; i < 1728; i += 256) {
        int sh = i / 192, ci = i % 192;
        bw[(size_t)co * 1728 + i] = f2bf(ls[ci * 9 + sh]);
    }
}

// ---- implicit-GEMM conv: M=73728 pixels, N=768, K=1728 ----
// 128x128 tile, BK=64, 4 waves of 4x4 16x16x32 bf16 MFMA, XOR-swizzled LDS.
__global__ __launch_bounds__(256) void conv_gemm_kernel(
    const unsigned short* __restrict__ xp, const unsigned short* __restrict__ bw,
    const float* __restrict__ bias, unsigned short* __restrict__ qkv)
{
    __shared__ __align__(16) char smem[34816];
    int bid = blockIdx.x;
    int brow = (bid / 6) * 128, bcol = (bid % 6) * 128;
    int tid = threadIdx.x, lane = tid & 63, wv = tid >> 6;
    int wr = wv >> 1, wc = wv & 1;

    // staging source/dest (loop-invariant parts)
    const unsigned short* srcA[4];
    const unsigned short* srcB[4];
    char* dstA[4];
    char* dstB[4];
#pragma unroll
    for (int i = 0; i < 4; ++i) {
        int s = i * 256 + tid;
        int row = s >> 3, c = s & 7;
        int p = brow + row;
        int n = p / 9216; int rem = p - n * 9216;
        int y = rem / 96; int xx = rem - y * 96;
        srcA[i] = xp + ((size_t)(n * PH + y) * PH + xx) * CIN + ((c ^ (row & 7)) << 3);
        srcB[i] = bw + (size_t)(bcol + row) * 1728 + ((c ^ (row & 7)) << 3);
        int uslot = i * 256 + (tid & ~63);   // wave-uniform
        dstA[i] = smem + uslot * 16;
        dstB[i] = smem + 16384 + uslot * 16;
    }

    // ds_read byte offsets per k-slab / fragment
    int aoff[2][4], boff[2][4];
#pragma unroll
    for (int ks = 0; ks < 2; ++ks) {
#pragma unroll
        for (int m = 0; m < 4; ++m) {
            int rowA = wr * 64 + m * 16 + (lane & 15);
            aoff[ks][m] = rowA * 128 + (((ks * 4 + (lane >> 4)) ^ (lane & 7)) << 4);
            int colB = wc * 64 + m * 16 + (lane & 15);
            boff[ks][m] = 16384 + colB * 128 + (((ks * 4 + (lane >> 4)) ^ (lane & 7)) << 4);
        }
    }

    f32x4 acc[4][4] = {};

    for (int step = 0; step < 27; ++step) {
        int shift = step / 3;
        int di = shift / 3, dj = shift % 3, kk = step - shift * 3;
        int aO = (di * PH + dj) * CIN + kk * 64;   // elements
        int bO = step * 64;                        // elements
#pragma unroll
        for (int i = 0; i < 4; ++i) gload16(srcA[i] + aO, dstA[i]);
#pragma unroll
        for (int i = 0; i < 4; ++i) gload16(srcB[i] + bO, dstB[i]);
        __syncthreads();
#pragma unroll
        for (int ks = 0; ks < 2; ++ks) {
            bf16x8 af[4], bf[4];
#pragma unroll
            for (int m = 0; m < 4; ++m) af[m] = *(const bf16x8*)(smem + aoff[ks][m]);
#pragma unroll
            for (int n = 0; n < 4; ++n) bf[n] = *(const bf16x8*)(smem + boff[ks][n]);
#pragma unroll
            for (int m = 0; m < 4; ++m)
#pragma unroll
                for (int n = 0; n < 4; ++n)
                    acc[m][n] = __builtin_amdgcn_mfma_f32_16x16x32_bf16(
                        af[m], bf[n], acc[m][n], 0, 0, 0);
        }
        __syncthreads();
    }

    // epilogue: bias add, LDS transpose (stride 136), coalesced bf16 store
    unsigned short* sc = (unsigned short*)smem;
    float bn[4];
#pragma unroll
    for (int n = 0; n < 4; ++n)
        bn[n] = bias[bcol + wc * 64 + n * 16 + (lane & 15)];
#pragma unroll
    for (int m = 0; m < 4; ++m)
#pragma unroll
        for (int n = 0; n < 4; ++n) {
            int col = wc * 64 + n * 16 + (lane & 15);
#pragma unroll
            for (int j = 0; j < 4; ++j) {
                int row = wr * 64 + m * 16 + (lane >> 4) * 4 + j;
                sc[row * 136 + col] = f2bf(acc[m][n][j] + bn[n]);
            }
        }
    __syncthreads();
#pragma unroll
    for (int i = 0; i < 8; ++i) {
        int idx = i * 256 + tid;
        int row = idx >> 4, ch = idx & 15;
        ushort8 pk = *(const ushort8*)(sc + row * 136 + ch * 8);
        *(ushort8*)(qkv + (size_t)(brow + row) * COUT + bcol + ch * 8) = pk;
    }
}

// ---- neighborhood attention: one wave per (pixel, head), lane = dim ----
template<int KS>
__global__ __launch_bounds__(256) void na_kernel(
    const unsigned short* __restrict__ qkv, float* __restrict__ out, int head)
{
    constexpr int PAD = KS / 2;
    __shared__ float sout[4][65];
    int bid = blockIdx.x;
    int xg = bid % 24;
    int y  = (bid / 24) % NH;
    int n  = bid / (24 * NH);
    int lane = threadIdx.x & 63;
    int wv   = threadIdx.x >> 6;
    int x = xg * 4 + wv;

    size_t pixbase = (((size_t)n * NH + y) * NW + x) * COUT + (size_t)head * 192;
    float q = bf2f(qkv[pixbase + lane]) * 0.125f;

    float m = -1e30f, l = 0.f, acc = 0.f;
    for (int di = 0; di < KS; ++di) {
        int iy = y + di - PAD;
        if (iy < 0 || iy >= NH) continue;
        for (int dj = 0; dj < KS; ++dj) {
            int ix = x + dj - PAD;
            if (ix < 0 || ix >= NW) continue;
            size_t nb = (((size_t)n * NH + iy) * NW + ix) * COUT + (size_t)head * 192;
            float kv = bf2f(qkv[nb + 64 + lane]);
            float t = q * kv;
#pragma unroll
            for (int off = 32; off >= 1; off >>= 1)
                t += __shfl_xor(t, off, 64);
            float s = t;
            if (s > m) {
                float r = __expf(m - s);
                l *= r; acc *= r; m = s;
            }
            float p = __expf(s - m);
            float vv = bf2f(qkv[nb + 128 + lane]);
            l += p;
            acc = fmaf(p, vv, acc);
        }
    }
    sout[wv][lane] = acc / l;
    __syncthreads();
    int d = threadIdx.x >> 2, xi = threadIdx.x & 3;
    float val = sout[xi][d];
    size_t o = (size_t)head * 4718592 + (size_t)n * 589824 +
               (size_t)d * 9216 + (size_t)y * 96 + (size_t)(xg * 4 + xi);
    out[o] = val;
}

extern "C" void kernel_launch(void* const* d_in, const int* in_sizes, int n_in,
                              void* d_out, int out_size, void* d_ws, size_t ws_size,
                              hipStream_t stream) {
    const float* x  = (const float*)d_in[0];
    const float* w  = (const float*)d_in[1];
    const float* b  = (const float*)d_in[2];
    float* out = (float*)d_out;

    unsigned short* qkv  = (unsigned short*)d_ws;                       // 113246208 B
    unsigned short* xpad = (unsigned short*)((char*)d_ws + 113246208);  // 29503488 B
    unsigned short* bw   = (unsigned short*)((char*)d_ws + 142749696);  // 2654208 B

    hipMemsetAsync(xpad, 0, 29503488, stream);
    pack_x_kernel<<<NB * NH * 6, 256, 0, stream>>>(x, xpad);
    pack_w_kernel<<<COUT, 256, 0, stream>>>(w, bw);
    conv_gemm_kernel<<<576 * 6, 256, 0, stream>>>(xpad, bw, b, qkv);

    const int na_grid = (NW / 4) * NH * NB;  // 18432
    na_kernel<3><<<na_grid, 256, 0, stream>>>(qkv, out, 0);
    na_kernel<5><<<na_grid, 256, 0, stream>>>(qkv, out, 1);
    na_kernel<7><<<na_grid, 256, 0, stream>>>(qkv, out, 2);
    na_kernel<9><<<na_grid, 256, 0, stream>>>(qkv, out, 3);
}

// Round 3
// 460.751 us; speedup vs baseline: 8.4508x; 2.5010x over previous
//
#include <hip/hip_runtime.h>
#include <hip/hip_bf16.h>

#define NH 96
#define NW 96
#define NB 8
#define CIN 192
#define COUT 768   // 4 heads * 3 * 64
#define PH 98      // padded spatial dim

typedef __attribute__((ext_vector_type(8))) unsigned short ushort8;
typedef __attribute__((ext_vector_type(8))) short bf16x8;
typedef __attribute__((ext_vector_type(4))) float f32x4;

static __device__ __forceinline__ unsigned short f2bf(float f) {
    unsigned int u = __float_as_uint(f);
    return (unsigned short)((u + 0x7fffu + ((u >> 16) & 1u)) >> 16);
}

typedef const __attribute__((address_space(1))) unsigned int gu32;
typedef __attribute__((address_space(3))) unsigned int lu32;
static __device__ __forceinline__ void gload16(const void* g, void* l) {
    __builtin_amdgcn_global_load_lds((gu32*)g, (lu32*)l, 16, 0, 0);
}

// ---- pack x: NCHW fp32 -> zero-padded NHWC bf16 [8][98][98][192] ----
__global__ __launch_bounds__(256) void pack_x_kernel(
    const float* __restrict__ x, unsigned short* __restrict__ xp)
{
    __shared__ float tile[32][97];
    int bid = blockIdx.x;
    int ct = bid % 6; int y = (bid / 6) % NH; int n = bid / (6 * NH);
    int tid = threadIdx.x;
    int c0 = ct * 32;
    for (int i = tid; i < 32 * 96; i += 256) {
        int c = i / 96, xx = i % 96;
        tile[c][xx] = x[(((size_t)n * CIN + c0 + c) * NH + y) * NW + xx];
    }
    __syncthreads();
    for (int i = tid; i < 96 * 4; i += 256) {
        int xx = i >> 2, ch = i & 3;
        ushort8 pk;
#pragma unroll
        for (int j = 0; j < 8; ++j) pk[j] = f2bf(tile[ch * 8 + j][xx]);
        *(ushort8*)(xp + ((size_t)(n * PH + y + 1) * PH + xx + 1) * CIN + c0 + ch * 8) = pk;
    }
}

// ---- pack w: [co][ci][3][3] fp32 -> [co][(di*3+dj)*192+ci] bf16 ----
__global__ __launch_bounds__(256) void pack_w_kernel(
    const float* __restrict__ w, unsigned short* __restrict__ bw)
{
    __shared__ float ls[1728];
    int co = blockIdx.x; int tid = threadIdx.x;
    for (int i = tid; i < 1728; i += 256) ls[i] = w[(size_t)co * 1728 + i];
    __syncthreads();
    for (int i = tid; i < 1728; i += 256) {
        int sh = i / 192, ci = i % 192;
        bw[(size_t)co * 1728 + i] = f2bf(ls[ci * 9 + sh]);
    }
}

// ---- implicit-GEMM conv: M=73728 pixels, N=768, K=1728 ----
// Q channels (c%192<64) pre-scaled by 0.125 so NA skips the scale.
__global__ __launch_bounds__(256) void conv_gemm_kernel(
    const unsigned short* __restrict__ xp, const unsigned short* __restrict__ bw,
    const float* __restrict__ bias, unsigned short* __restrict__ qkv)
{
    __shared__ __align__(16) char smem[34816];
    int bid = blockIdx.x;
    int brow = (bid / 6) * 128, bcol = (bid % 6) * 128;
    int tid = threadIdx.x, lane = tid & 63, wv = tid >> 6;
    int wr = wv >> 1, wc = wv & 1;

    const unsigned short* srcA[4];
    const unsigned short* srcB[4];
    char* dstA[4];
    char* dstB[4];
#pragma unroll
    for (int i = 0; i < 4; ++i) {
        int s = i * 256 + tid;
        int row = s >> 3, c = s & 7;
        int p = brow + row;
        int n = p / 9216; int rem = p - n * 9216;
        int y = rem / 96; int xx = rem - y * 96;
        srcA[i] = xp + ((size_t)(n * PH + y) * PH + xx) * CIN + ((c ^ (row & 7)) << 3);
        srcB[i] = bw + (size_t)(bcol + row) * 1728 + ((c ^ (row & 7)) << 3);
        int uslot = i * 256 + (tid & ~63);
        dstA[i] = smem + uslot * 16;
        dstB[i] = smem + 16384 + uslot * 16;
    }

    int aoff[2][4], boff[2][4];
#pragma unroll
    for (int ks = 0; ks < 2; ++ks) {
#pragma unroll
        for (int m = 0; m < 4; ++m) {
            int rowA = wr * 64 + m * 16 + (lane & 15);
            aoff[ks][m] = rowA * 128 + (((ks * 4 + (lane >> 4)) ^ (lane & 7)) << 4);
            int colB = wc * 64 + m * 16 + (lane & 15);
            boff[ks][m] = 16384 + colB * 128 + (((ks * 4 + (lane >> 4)) ^ (lane & 7)) << 4);
        }
    }

    f32x4 acc[4][4] = {};

    for (int step = 0; step < 27; ++step) {
        int shift = step / 3;
        int di = shift / 3, dj = shift % 3, kk = step - shift * 3;
        int aO = (di * PH + dj) * CIN + kk * 64;
        int bO = step * 64;
#pragma unroll
        for (int i = 0; i < 4; ++i) gload16(srcA[i] + aO, dstA[i]);
#pragma unroll
        for (int i = 0; i < 4; ++i) gload16(srcB[i] + bO, dstB[i]);
        __syncthreads();
#pragma unroll
        for (int ks = 0; ks < 2; ++ks) {
            bf16x8 af[4], bf[4];
#pragma unroll
            for (int m = 0; m < 4; ++m) af[m] = *(const bf16x8*)(smem + aoff[ks][m]);
#pragma unroll
            for (int n = 0; n < 4; ++n) bf[n] = *(const bf16x8*)(smem + boff[ks][n]);
#pragma unroll
            for (int m = 0; m < 4; ++m)
#pragma unroll
                for (int n = 0; n < 4; ++n)
                    acc[m][n] = __builtin_amdgcn_mfma_f32_16x16x32_bf16(
                        af[m], bf[n], acc[m][n], 0, 0, 0);
        }
        __syncthreads();
    }

    unsigned short* sc = (unsigned short*)smem;
    float bn[4];
#pragma unroll
    for (int n = 0; n < 4; ++n)
        bn[n] = bias[bcol + wc * 64 + n * 16 + (lane & 15)];
#pragma unroll
    for (int m = 0; m < 4; ++m)
#pragma unroll
        for (int n = 0; n < 4; ++n) {
            int col = wc * 64 + n * 16 + (lane & 15);
            int cabs = bcol + col;
            float scale = ((cabs % 192) < 64) ? 0.125f : 1.0f;
#pragma unroll
            for (int j = 0; j < 4; ++j) {
                int row = wr * 64 + m * 16 + (lane >> 4) * 4 + j;
                sc[row * 136 + col] = f2bf((acc[m][n][j] + bn[n]) * scale);
            }
        }
    __syncthreads();
#pragma unroll
    for (int i = 0; i < 8; ++i) {
        int idx = i * 256 + tid;
        int row = idx >> 4, ch = idx & 15;
        ushort8 pk = *(const ushort8*)(sc + row * 136 + ch * 8);
        *(ushort8*)(qkv + (size_t)(brow + row) * COUT + bcol + ch * 8) = pk;
    }
}

// ---- pack V^T for one head: qkv NHWC -> vt[n][d][y][x] bf16 ----
__global__ __launch_bounds__(256) void pack_vt_kernel(
    const unsigned short* __restrict__ qkv, unsigned short* __restrict__ vt, int head)
{
    __shared__ unsigned short tile[96][80];
    int y = blockIdx.x % 96, n = blockIdx.x / 96;
    int tid = threadIdx.x;
    for (int i = tid; i < 768; i += 256) {
        int px = i >> 3, c8 = i & 7;
        ushort8 v = *(const ushort8*)(qkv + ((size_t)((n * 96 + y) * 96 + px)) * 768
                                      + head * 192 + 128 + c8 * 8);
        *(ushort8*)(&tile[px][c8 * 8]) = v;
    }
    __syncthreads();
    for (int i = tid; i < 768; i += 256) {
        int d = i / 12, xb = i % 12;
        ushort8 pk;
#pragma unroll
        for (int j = 0; j < 8; ++j) pk[j] = tile[xb * 8 + j][d];
        *(ushort8*)(vt + (((size_t)n * 64 + d) * 96 + y) * 96 + xb * 8) = pk;
    }
}

// ---- MFMA neighborhood attention ----
// wave = 16-pixel x-strip; block = 6 waves = one full row (n,y).
// Key window: 32 keys starting at W = x0-8 (covers pad<=4, 16B-aligned V).
template<int KS>
__global__ __launch_bounds__(384, 3) void na_mfma_kernel(
    const unsigned short* __restrict__ qkv, const unsigned short* __restrict__ vt,
    float* __restrict__ out, int head)
{
    constexpr int PAD = KS / 2;
    __shared__ float sO[64][97];
    int bid = blockIdx.x;
    int y = bid % 96, n = bid / 96;
    int tid = threadIdx.x;
    int wv = tid >> 6, lane = tid & 63;
    int g = lane >> 4, pix = lane & 15;
    int x0 = wv * 16;
    int x = x0 + pix;        // pixel when lane&15 is in C-col / B-row role
    int W = x0 - 8;          // key window start

    // Q B-frags: pixel = lane&15, dims (lane>>4)*8.. (+32 for second half)
    size_t qbase = ((size_t)((n * 96 + y) * 96 + x)) * 768 + (size_t)head * 192;
    bf16x8 qf0 = *(const bf16x8*)(qkv + qbase + g * 8);
    bf16x8 qf1 = *(const bf16x8*)(qkv + qbase + 32 + g * 8);

    f32x4 s[KS][2];
#pragma unroll
    for (int di = 0; di < KS; ++di)
#pragma unroll
        for (int kt = 0; kt < 2; ++kt)
#pragma unroll
            for (int r = 0; r < 4; ++r) s[di][kt][r] = -1e30f;

    // ---- S^T = mfma(K, Q) ----
#pragma unroll
    for (int di = 0; di < KS; ++di) {
        int iy = y + di - PAD;
        if (iy < 0 || iy >= 96) continue;
#pragma unroll
        for (int kt = 0; kt < 2; ++kt) {
            int kix_l = W + kt * 16 + pix;           // pix in key (A-row) role
            int ixc = min(max(kix_l, 0), 95);
            size_t kbase = ((size_t)((n * 96 + iy) * 96 + ixc)) * 768
                           + (size_t)head * 192 + 64;
            bf16x8 kf0 = *(const bf16x8*)(qkv + kbase + g * 8);
            bf16x8 kf1 = *(const bf16x8*)(qkv + kbase + 32 + g * 8);
            f32x4 t = {};
            t = __builtin_amdgcn_mfma_f32_16x16x32_bf16(kf0, qf0, t, 0, 0, 0);
            t = __builtin_amdgcn_mfma_f32_16x16x32_bf16(kf1, qf1, t, 0, 0, 0);
#pragma unroll
            for (int r = 0; r < 4; ++r) {
                int kix = W + kt * 16 + g * 4 + r;    // key of C-row (g*4+r)
                bool valid = ((unsigned)(kix - x + PAD) <= (unsigned)(2 * PAD)) &&
                             ((unsigned)kix < 96u);
                s[di][kt][r] = valid ? t[r] : -1e30f;
            }
        }
    }

    // ---- softmax over all taps (pixel = lane&15; keys lane-local) ----
    float m = -3.0e38f;
#pragma unroll
    for (int di = 0; di < KS; ++di)
#pragma unroll
        for (int kt = 0; kt < 2; ++kt)
#pragma unroll
            for (int r = 0; r < 4; ++r) m = fmaxf(m, s[di][kt][r]);
    m = fmaxf(m, __shfl_xor(m, 16, 64));
    m = fmaxf(m, __shfl_xor(m, 32, 64));
    float l = 0.f;
#pragma unroll
    for (int di = 0; di < KS; ++di)
#pragma unroll
        for (int kt = 0; kt < 2; ++kt)
#pragma unroll
            for (int r = 0; r < 4; ++r) {
                float p = __expf(s[di][kt][r] - m);
                s[di][kt][r] = p;
                l += p;
            }
    l += __shfl_xor(l, 16, 64);
    l += __shfl_xor(l, 32, 64);

    // ---- PV ----
    f32x4 O[4] = {};
    int addrA = ((2 * (g & 1)) * 16 + pix) * 4;
    int addrB = addrA + 64;
    bool kthi = (g >> 1) != 0;
#pragma unroll
    for (int di = 0; di < KS; ++di) {
        int iy = y + di - PAD;
        if (iy < 0 || iy >= 96) continue;
        unsigned int w0[2], w1[2];
#pragma unroll
        for (int kt = 0; kt < 2; ++kt) {
            asm("v_cvt_pk_bf16_f32 %0, %1, %2"
                : "=v"(w0[kt]) : "v"(s[di][kt][0]), "v"(s[di][kt][1]));
            asm("v_cvt_pk_bf16_f32 %0, %1, %2"
                : "=v"(w1[kt]) : "v"(s[di][kt][2]), "v"(s[di][kt][3]));
        }
        int a0 = __builtin_amdgcn_ds_bpermute(addrA, (int)w0[0]);
        int b0 = __builtin_amdgcn_ds_bpermute(addrA, (int)w0[1]);
        int a1 = __builtin_amdgcn_ds_bpermute(addrA, (int)w1[0]);
        int b1 = __builtin_amdgcn_ds_bpermute(addrA, (int)w1[1]);
        int a2 = __builtin_amdgcn_ds_bpermute(addrB, (int)w0[0]);
        int b2 = __builtin_amdgcn_ds_bpermute(addrB, (int)w0[1]);
        int a3 = __builtin_amdgcn_ds_bpermute(addrB, (int)w1[0]);
        int b3 = __builtin_amdgcn_ds_bpermute(addrB, (int)w1[1]);
        union { int u[4]; bf16x8 v; } pa;
        pa.u[0] = kthi ? b0 : a0;
        pa.u[1] = kthi ? b1 : a1;
        pa.u[2] = kthi ? b2 : a2;
        pa.u[3] = kthi ? b3 : a3;
#pragma unroll
        for (int dc = 0; dc < 4; ++dc) {
            long voff = ((long)((n * 64 + dc * 16 + pix) * 96 + iy)) * 96 + (W + g * 8);
            bf16x8 vf = *(const bf16x8*)(vt + voff);
            O[dc] = __builtin_amdgcn_mfma_f32_16x16x32_bf16(pa.v, vf, O[dc], 0, 0, 0);
        }
    }

    // ---- normalize + transpose-store ----
    float linv = 1.0f / l;   // for pixel = pix
    float linvj[4];
#pragma unroll
    for (int j = 0; j < 4; ++j)
        linvj[j] = __uint_as_float((unsigned)__builtin_amdgcn_ds_bpermute(
            (4 * g + j) * 4, (int)__float_as_uint(linv)));
#pragma unroll
    for (int dc = 0; dc < 4; ++dc)
#pragma unroll
        for (int j = 0; j < 4; ++j)
            sO[dc * 16 + pix][x0 + g * 4 + j] = O[dc][j] * linvj[j];
    __syncthreads();
    for (int i = tid; i < 1536; i += 384) {
        int d = i / 24, xq = i % 24;
        float4 v4 = { sO[d][xq * 4], sO[d][xq * 4 + 1],
                      sO[d][xq * 4 + 2], sO[d][xq * 4 + 3] };
        *(float4*)(out + ((size_t)(head * 8 + n) * 64 + d) * 9216
                   + y * 96 + xq * 4) = v4;
    }
}

extern "C" void kernel_launch(void* const* d_in, const int* in_sizes, int n_in,
                              void* d_out, int out_size, void* d_ws, size_t ws_size,
                              hipStream_t stream) {
    const float* x  = (const float*)d_in[0];
    const float* w  = (const float*)d_in[1];
    const float* b  = (const float*)d_in[2];
    float* out = (float*)d_out;

    unsigned short* qkv  = (unsigned short*)d_ws;                       // 113246208 B
    unsigned short* xpad = (unsigned short*)((char*)d_ws + 113246208);  // 29503488 B
    unsigned short* bw   = (unsigned short*)((char*)d_ws + 142749696);  // 2654208 B
    // vt reuses the xpad+bw region after conv (9.44 MB + slack)
    unsigned short* vt   = (unsigned short*)((char*)d_ws + 113246208 + 16384);

    hipMemsetAsync(xpad, 0, 29503488, stream);
    pack_x_kernel<<<NB * NH * 6, 256, 0, stream>>>(x, xpad);
    pack_w_kernel<<<COUT, 256, 0, stream>>>(w, bw);
    conv_gemm_kernel<<<576 * 6, 256, 0, stream>>>(xpad, bw, b, qkv);

    pack_vt_kernel<<<768, 256, 0, stream>>>(qkv, vt, 0);
    na_mfma_kernel<3><<<768, 384, 0, stream>>>(qkv, vt, out, 0);
    pack_vt_kernel<<<768, 256, 0, stream>>>(qkv, vt, 1);
    na_mfma_kernel<5><<<768, 384, 0, stream>>>(qkv, vt, out, 1);
    pack_vt_kernel<<<768, 256, 0, stream>>>(qkv, vt, 2);
    na_mfma_kernel<7><<<768, 384, 0, stream>>>(qkv, vt, out, 2);
    pack_vt_kernel<<<768, 256, 0, stream>>>(qkv, vt, 3);
    na_mfma_kernel<9><<<768, 384, 0, stream>>>(qkv, vt, out, 3);
}

// Round 4
// 422.991 us; speedup vs baseline: 9.2052x; 1.0893x over previous
//
#include <hip/hip_runtime.h>
#include <hip/hip_bf16.h>

#define NH 96
#define NW 96
#define NB 8
#define CIN 192
#define COUT 768   // 4 heads * 3 * 64
#define PH 98      // padded spatial dim

typedef __attribute__((ext_vector_type(8))) unsigned short ushort8;
typedef __attribute__((ext_vector_type(8))) short bf16x8;
typedef __attribute__((ext_vector_type(4))) float f32x4;

static __device__ __forceinline__ unsigned short f2bf(float f) {
    unsigned int u = __float_as_uint(f);
    return (unsigned short)((u + 0x7fffu + ((u >> 16) & 1u)) >> 16);
}

typedef const __attribute__((address_space(1))) unsigned int gu32;
typedef __attribute__((address_space(3))) unsigned int lu32;
static __device__ __forceinline__ void gload16(const void* g, void* l) {
    __builtin_amdgcn_global_load_lds((gu32*)g, (lu32*)l, 16, 0, 0);
}

// ---- pack x: NCHW fp32 -> zero-padded NHWC bf16 [8][98][98][192] ----
__global__ __launch_bounds__(256) void pack_x_kernel(
    const float* __restrict__ x, unsigned short* __restrict__ xp)
{
    __shared__ float tile[32][97];
    int bid = blockIdx.x;
    int ct = bid % 6; int y = (bid / 6) % NH; int n = bid / (6 * NH);
    int tid = threadIdx.x;
    int c0 = ct * 32;
    for (int i = tid; i < 32 * 96; i += 256) {
        int c = i / 96, xx = i % 96;
        tile[c][xx] = x[(((size_t)n * CIN + c0 + c) * NH + y) * NW + xx];
    }
    __syncthreads();
    for (int i = tid; i < 96 * 4; i += 256) {
        int xx = i >> 2, ch = i & 3;
        ushort8 pk;
#pragma unroll
        for (int j = 0; j < 8; ++j) pk[j] = f2bf(tile[ch * 8 + j][xx]);
        *(ushort8*)(xp + ((size_t)(n * PH + y + 1) * PH + xx + 1) * CIN + c0 + ch * 8) = pk;
    }
}

// ---- pack w: [co][ci][3][3] fp32 -> [co][(di*3+dj)*192+ci] bf16 ----
__global__ __launch_bounds__(256) void pack_w_kernel(
    const float* __restrict__ w, unsigned short* __restrict__ bw)
{
    __shared__ float ls[1728];
    int co = blockIdx.x; int tid = threadIdx.x;
    for (int i = tid; i < 1728; i += 256) ls[i] = w[(size_t)co * 1728 + i];
    __syncthreads();
    for (int i = tid; i < 1728; i += 256) {
        int sh = i / 192, ci = i % 192;
        bw[(size_t)co * 1728 + i] = f2bf(ls[ci * 9 + sh]);
    }
}

// ---- implicit-GEMM conv: M=73728, N=768, K=1728 ----
// 128x128 tile, BK=32, double-buffered LDS, 2-phase pipeline (stage-ahead,
// one barrier/step). XCD-swizzled grid. Q pre-scaled by 0.125.
// Epilogue also writes V channels in vt[n][d][y][x] layout (fused pack_vt).
__global__ __launch_bounds__(256, 4) void conv_gemm_kernel(
    const unsigned short* __restrict__ xp, const unsigned short* __restrict__ bw,
    const float* __restrict__ bias, unsigned short* __restrict__ qkv,
    unsigned short* __restrict__ vt)
{
    __shared__ __align__(16) char smem[32768];
    int bid = (blockIdx.x & 7) * 432 + (blockIdx.x >> 3);   // XCD swizzle
    int brow = (bid / 6) * 128, bcol = (bid % 6) * 128;
    int tid = threadIdx.x, lane = tid & 63, wv = tid >> 6;
    int wr = wv >> 1, wc = wv & 1;

    // staging geometry: tile half = 128 rows x 32 bf16 (8KB) = 512 x 16B
    const unsigned short* srcA[2];
    const unsigned short* srcB[2];
    char* dstA[2];
    char* dstB[2];
#pragma unroll
    for (int i = 0; i < 2; ++i) {
        int s = i * 256 + tid;
        int row = s >> 2, c = s & 3;
        int p = brow + row;
        int n = p / 9216; int rem = p - n * 9216;
        int y = rem / 96; int xx = rem - y * 96;
        int csw = (c ^ ((row >> 1) & 3)) << 3;   // swizzled chunk (elements)
        srcA[i] = xp + ((size_t)(n * PH + y) * PH + xx) * CIN + csw;
        srcB[i] = bw + (size_t)(bcol + row) * 1728 + csw;
        int uslot = i * 256 + (tid & ~63);       // wave-uniform
        dstA[i] = smem + uslot * 16;
        dstB[i] = smem + 8192 + uslot * 16;
    }

    // ds_read byte offsets (within a buffer)
    int aoff[4], boff[4];
#pragma unroll
    for (int m = 0; m < 4; ++m) {
        int rowA = wr * 64 + m * 16 + (lane & 15);
        aoff[m] = rowA * 64 + (((lane >> 4) ^ ((rowA >> 1) & 3)) << 4);
        int colB = wc * 64 + m * 16 + (lane & 15);
        boff[m] = 8192 + colB * 64 + (((lane >> 4) ^ ((colB >> 1) & 3)) << 4);
    }

    // prologue: stage step 0 into buffer 0
#pragma unroll
    for (int i = 0; i < 2; ++i) { gload16(srcA[i], dstA[i]); gload16(srcB[i], dstB[i]); }
    __syncthreads();

    f32x4 acc[4][4] = {};

    for (int t = 0; t < 54; ++t) {
        int cur = (t & 1) << 14;
        int nxt = cur ^ 16384;
        if (t < 53) {
            int step = t + 1;
            int shift = step / 6, kk = step - shift * 6;
            int aO = ((shift / 3) * PH + (shift % 3)) * CIN + kk * 32;
            int bO = step * 32;
#pragma unroll
            for (int i = 0; i < 2; ++i) {
                gload16(srcA[i] + aO, dstA[i] + nxt);
                gload16(srcB[i] + bO, dstB[i] + nxt);
            }
        }
        bf16x8 af[4], bf[4];
#pragma unroll
        for (int m = 0; m < 4; ++m) af[m] = *(const bf16x8*)(smem + cur + aoff[m]);
#pragma unroll
        for (int n = 0; n < 4; ++n) bf[n] = *(const bf16x8*)(smem + cur + boff[n]);
#pragma unroll
        for (int m = 0; m < 4; ++m)
#pragma unroll
            for (int n = 0; n < 4; ++n)
                acc[m][n] = __builtin_amdgcn_mfma_f32_16x16x32_bf16(
                    af[m], bf[n], acc[m][n], 0, 0, 0);
        __syncthreads();   // vmcnt(0)+lgkmcnt(0)+barrier: next tile landed
    }

    // ---- epilogue: sc[row][col^((row&7)<<3)] stride 128 (32KB, XOR-swizzled) ----
    unsigned short* sc = (unsigned short*)smem;
    float bn[4];
#pragma unroll
    for (int n = 0; n < 4; ++n)
        bn[n] = bias[bcol + wc * 64 + n * 16 + (lane & 15)];
#pragma unroll
    for (int m = 0; m < 4; ++m)
#pragma unroll
        for (int n = 0; n < 4; ++n) {
            int col = wc * 64 + n * 16 + (lane & 15);
            int cabs = bcol + col;
            float scale = ((cabs % 192) < 64) ? 0.125f : 1.0f;
#pragma unroll
            for (int j = 0; j < 4; ++j) {
                int row = wr * 64 + m * 16 + (lane >> 4) * 4 + j;
                sc[row * 128 + (col ^ ((row & 7) << 3))] =
                    f2bf((acc[m][n][j] + bn[n]) * scale);
            }
        }
    __syncthreads();
    // qkv store (coalesced 16B)
#pragma unroll
    for (int i = 0; i < 8; ++i) {
        int idx = i * 256 + tid;
        int row = idx >> 4, ch = idx & 15;
        ushort8 pk = *(const ushort8*)(sc + row * 128 + ((ch * 8) ^ ((row & 7) << 3)));
        *(ushort8*)(qkv + (size_t)(brow + row) * COUT + bcol + ch * 8) = pk;
    }
    // fused V^T gather: V channels are a 64-aligned subrange (if present)
    int cstart = -1;
    if (((bcol + 0) % 192) >= 128) cstart = 0;
    if (((bcol + 64) % 192) >= 128) cstart = 64;
    if (cstart >= 0) {
        int head = (bcol + cstart) / 192;
        unsigned short* vth = vt + (size_t)head * 4718592;  // 8*64*9216
        int nblk = brow / 9216;
        int prem = brow - nblk * 9216;
#pragma unroll
        for (int it = 0; it < 4; ++it) {
            int i = it * 256 + tid;
            int d = i & 63, pxb = i >> 6;
            ushort8 pk;
#pragma unroll
            for (int j = 0; j < 8; ++j) {
                int px = pxb * 8 + j;
                pk[j] = sc[px * 128 + ((cstart + d) ^ ((px & 7) << 3))];
            }
            *(ushort8*)(vth + ((size_t)(nblk * 64 + d)) * 9216 + prem + pxb * 8) = pk;
        }
    }
}

// ---- MFMA neighborhood attention ----
template<int KS>
__global__ __launch_bounds__(384, 3) void na_mfma_kernel(
    const unsigned short* __restrict__ qkv, const unsigned short* __restrict__ vt,
    float* __restrict__ out, int head)
{
    constexpr int PAD = KS / 2;
    __shared__ float sO[64][97];
    int bid = blockIdx.x;
    int y = bid % 96, n = bid / 96;
    int tid = threadIdx.x;
    int wv = tid >> 6, lane = tid & 63;
    int g = lane >> 4, pix = lane & 15;
    int x0 = wv * 16;
    int x = x0 + pix;
    int W = x0 - 8;

    size_t qbase = ((size_t)((n * 96 + y) * 96 + x)) * 768 + (size_t)head * 192;
    bf16x8 qf0 = *(const bf16x8*)(qkv + qbase + g * 8);
    bf16x8 qf1 = *(const bf16x8*)(qkv + qbase + 32 + g * 8);

    f32x4 s[KS][2];
#pragma unroll
    for (int di = 0; di < KS; ++di)
#pragma unroll
        for (int kt = 0; kt < 2; ++kt)
#pragma unroll
            for (int r = 0; r < 4; ++r) s[di][kt][r] = -1e30f;

#pragma unroll
    for (int di = 0; di < KS; ++di) {
        int iy = y + di - PAD;
        if (iy < 0 || iy >= 96) continue;
#pragma unroll
        for (int kt = 0; kt < 2; ++kt) {
            int kix_l = W + kt * 16 + pix;
            int ixc = min(max(kix_l, 0), 95);
            size_t kbase = ((size_t)((n * 96 + iy) * 96 + ixc)) * 768
                           + (size_t)head * 192 + 64;
            bf16x8 kf0 = *(const bf16x8*)(qkv + kbase + g * 8);
            bf16x8 kf1 = *(const bf16x8*)(qkv + kbase + 32 + g * 8);
            f32x4 t = {};
            t = __builtin_amdgcn_mfma_f32_16x16x32_bf16(kf0, qf0, t, 0, 0, 0);
            t = __builtin_amdgcn_mfma_f32_16x16x32_bf16(kf1, qf1, t, 0, 0, 0);
#pragma unroll
            for (int r = 0; r < 4; ++r) {
                int kix = W + kt * 16 + g * 4 + r;
                bool valid = ((unsigned)(kix - x + PAD) <= (unsigned)(2 * PAD)) &&
                             ((unsigned)kix < 96u);
                s[di][kt][r] = valid ? t[r] : -1e30f;
            }
        }
    }

    float m = -3.0e38f;
#pragma unroll
    for (int di = 0; di < KS; ++di)
#pragma unroll
        for (int kt = 0; kt < 2; ++kt)
#pragma unroll
            for (int r = 0; r < 4; ++r) m = fmaxf(m, s[di][kt][r]);
    m = fmaxf(m, __shfl_xor(m, 16, 64));
    m = fmaxf(m, __shfl_xor(m, 32, 64));
    float l = 0.f;
#pragma unroll
    for (int di = 0; di < KS; ++di)
#pragma unroll
        for (int kt = 0; kt < 2; ++kt)
#pragma unroll
            for (int r = 0; r < 4; ++r) {
                float p = __expf(s[di][kt][r] - m);
                s[di][kt][r] = p;
                l += p;
            }
    l += __shfl_xor(l, 16, 64);
    l += __shfl_xor(l, 32, 64);

    f32x4 O[4] = {};
    int addrA = ((2 * (g & 1)) * 16 + pix) * 4;
    int addrB = addrA + 64;
    bool kthi = (g >> 1) != 0;
#pragma unroll
    for (int di = 0; di < KS; ++di) {
        int iy = y + di - PAD;
        if (iy < 0 || iy >= 96) continue;
        unsigned int w0[2], w1[2];
#pragma unroll
        for (int kt = 0; kt < 2; ++kt) {
            asm("v_cvt_pk_bf16_f32 %0, %1, %2"
                : "=v"(w0[kt]) : "v"(s[di][kt][0]), "v"(s[di][kt][1]));
            asm("v_cvt_pk_bf16_f32 %0, %1, %2"
                : "=v"(w1[kt]) : "v"(s[di][kt][2]), "v"(s[di][kt][3]));
        }
        int a0 = __builtin_amdgcn_ds_bpermute(addrA, (int)w0[0]);
        int b0 = __builtin_amdgcn_ds_bpermute(addrA, (int)w0[1]);
        int a1 = __builtin_amdgcn_ds_bpermute(addrA, (int)w1[0]);
        int b1 = __builtin_amdgcn_ds_bpermute(addrA, (int)w1[1]);
        int a2 = __builtin_amdgcn_ds_bpermute(addrB, (int)w0[0]);
        int b2 = __builtin_amdgcn_ds_bpermute(addrB, (int)w0[1]);
        int a3 = __builtin_amdgcn_ds_bpermute(addrB, (int)w1[0]);
        int b3 = __builtin_amdgcn_ds_bpermute(addrB, (int)w1[1]);
        union { int u[4]; bf16x8 v; } pa;
        pa.u[0] = kthi ? b0 : a0;
        pa.u[1] = kthi ? b1 : a1;
        pa.u[2] = kthi ? b2 : a2;
        pa.u[3] = kthi ? b3 : a3;
#pragma unroll
        for (int dc = 0; dc < 4; ++dc) {
            long voff = ((long)((n * 64 + dc * 16 + pix) * 96 + iy)) * 96 + (W + g * 8);
            bf16x8 vf = *(const bf16x8*)(vt + voff);
            O[dc] = __builtin_amdgcn_mfma_f32_16x16x32_bf16(pa.v, vf, O[dc], 0, 0, 0);
        }
    }

    float linv = 1.0f / l;
    float linvj[4];
#pragma unroll
    for (int j = 0; j < 4; ++j)
        linvj[j] = __uint_as_float((unsigned)__builtin_amdgcn_ds_bpermute(
            (4 * g + j) * 4, (int)__float_as_uint(linv)));
#pragma unroll
    for (int dc = 0; dc < 4; ++dc)
#pragma unroll
        for (int j = 0; j < 4; ++j)
            sO[dc * 16 + pix][x0 + g * 4 + j] = O[dc][j] * linvj[j];
    __syncthreads();
    for (int i = tid; i < 1536; i += 384) {
        int d = i / 24, xq = i % 24;
        float4 v4 = { sO[d][xq * 4], sO[d][xq * 4 + 1],
                      sO[d][xq * 4 + 2], sO[d][xq * 4 + 3] };
        *(float4*)(out + ((size_t)(head * 8 + n) * 64 + d) * 9216
                   + y * 96 + xq * 4) = v4;
    }
}

extern "C" void kernel_launch(void* const* d_in, const int* in_sizes, int n_in,
                              void* d_out, int out_size, void* d_ws, size_t ws_size,
                              hipStream_t stream) {
    const float* x  = (const float*)d_in[0];
    const float* w  = (const float*)d_in[1];
    const float* b  = (const float*)d_in[2];
    float* out = (float*)d_out;

    unsigned short* qkv  = (unsigned short*)d_ws;                       // 113246208 B
    unsigned short* xpad = (unsigned short*)((char*)d_ws + 113246208);  // 29503488 B
    unsigned short* bw   = (unsigned short*)((char*)d_ws + 142749696);  // 2654208 B

    // vt (4 heads x 9.44MB bf16) lives in d_out's upper half (free until NA2/NA3)
    unsigned short* vtb  = (unsigned short*)((char*)d_out + 37748736);
    // NA3's vt copy goes to the dead xpad region (free after conv)
    unsigned short* vtws = xpad;

    hipMemsetAsync(xpad, 0, 29503488, stream);
    pack_x_kernel<<<NB * NH * 6, 256, 0, stream>>>(x, xpad);
    pack_w_kernel<<<COUT, 256, 0, stream>>>(w, bw);
    conv_gemm_kernel<<<3456, 256, 0, stream>>>(xpad, bw, b, qkv, vtb);

    hipMemcpyAsync(vtws, vtb + (size_t)3 * 4718592, 9437184,
                   hipMemcpyDeviceToDevice, stream);

    na_mfma_kernel<3><<<768, 384, 0, stream>>>(qkv, vtb,               out, 0);
    na_mfma_kernel<5><<<768, 384, 0, stream>>>(qkv, vtb + 4718592,     out, 1);
    na_mfma_kernel<7><<<768, 384, 0, stream>>>(qkv, vtb + 2 * 4718592, out, 2);
    na_mfma_kernel<9><<<768, 384, 0, stream>>>(qkv, vtws,              out, 3);
}

// Round 5
// 404.656 us; speedup vs baseline: 9.6223x; 1.0453x over previous
//
#include <hip/hip_runtime.h>
#include <hip/hip_bf16.h>

#define NH 96
#define NW 96
#define NB 8
#define CIN 192
#define COUT 768   // 4 heads * 3 * 64
#define PH 98      // padded spatial dim

typedef __attribute__((ext_vector_type(8))) unsigned short ushort8;
typedef __attribute__((ext_vector_type(8))) short bf16x8;
typedef __attribute__((ext_vector_type(4))) float f32x4;

static __device__ __forceinline__ unsigned short f2bf(float f) {
    unsigned int u = __float_as_uint(f);
    return (unsigned short)((u + 0x7fffu + ((u >> 16) & 1u)) >> 16);
}

typedef const __attribute__((address_space(1))) unsigned int gu32;
typedef __attribute__((address_space(3))) unsigned int lu32;
static __device__ __forceinline__ void gload16(const void* g, void* l) {
    __builtin_amdgcn_global_load_lds((gu32*)g, (lu32*)l, 16, 0, 0);
}

// ---- pack x: NCHW fp32 -> zero-padded NHWC bf16 [8][98][98][192] ----
__global__ __launch_bounds__(256) void pack_x_kernel(
    const float* __restrict__ x, unsigned short* __restrict__ xp)
{
    __shared__ float tile[32][97];
    int bid = blockIdx.x;
    int ct = bid % 6; int y = (bid / 6) % NH; int n = bid / (6 * NH);
    int tid = threadIdx.x;
    int c0 = ct * 32;
    for (int i = tid; i < 32 * 96; i += 256) {
        int c = i / 96, xx = i % 96;
        tile[c][xx] = x[(((size_t)n * CIN + c0 + c) * NH + y) * NW + xx];
    }
    __syncthreads();
    for (int i = tid; i < 96 * 4; i += 256) {
        int xx = i >> 2, ch = i & 3;
        ushort8 pk;
#pragma unroll
        for (int j = 0; j < 8; ++j) pk[j] = f2bf(tile[ch * 8 + j][xx]);
        *(ushort8*)(xp + ((size_t)(n * PH + y + 1) * PH + xx + 1) * CIN + c0 + ch * 8) = pk;
    }
}

// ---- pack w: [co][ci][3][3] fp32 -> [co][(di*3+dj)*192+ci] bf16 ----
__global__ __launch_bounds__(256) void pack_w_kernel(
    const float* __restrict__ w, unsigned short* __restrict__ bw)
{
    __shared__ float ls[1728];
    int co = blockIdx.x; int tid = threadIdx.x;
    for (int i = tid; i < 1728; i += 256) ls[i] = w[(size_t)co * 1728 + i];
    __syncthreads();
    for (int i = tid; i < 1728; i += 256) {
        int sh = i / 192, ci = i % 192;
        bw[(size_t)co * 1728 + i] = f2bf(ls[ci * 9 + sh]);
    }
}

// ---- implicit-GEMM conv: M=73728, N=768, K=1728 ----
// 128x128 tile, BK=32, TRIPLE-buffered LDS, counted-vmcnt pipeline (stage 2
// tiles ahead, s_waitcnt vmcnt(4) per step, never drain in-loop). XCD swizzle.
// Q pre-scaled by 0.125. Epilogue fuses V^T pack.
#define CONV_COMPUTE(CUR)                                                      \
    {                                                                          \
        bf16x8 af[4], bf[4];                                                   \
        _Pragma("unroll")                                                      \
        for (int m2 = 0; m2 < 4; ++m2)                                         \
            af[m2] = *(const bf16x8*)(smem + (CUR) + aoff[m2]);                \
        _Pragma("unroll")                                                      \
        for (int n2 = 0; n2 < 4; ++n2)                                         \
            bf[n2] = *(const bf16x8*)(smem + (CUR) + boff[n2]);                \
        __builtin_amdgcn_s_setprio(1);                                         \
        _Pragma("unroll")                                                      \
        for (int m2 = 0; m2 < 4; ++m2)                                         \
            _Pragma("unroll")                                                  \
            for (int n2 = 0; n2 < 4; ++n2)                                     \
                acc[m2][n2] = __builtin_amdgcn_mfma_f32_16x16x32_bf16(         \
                    af[m2], bf[n2], acc[m2][n2], 0, 0, 0);                     \
        __builtin_amdgcn_s_setprio(0);                                         \
    }

__global__ __launch_bounds__(256, 3) void conv_gemm_kernel(
    const unsigned short* __restrict__ xp, const unsigned short* __restrict__ bw,
    const float* __restrict__ bias, unsigned short* __restrict__ qkv,
    unsigned short* __restrict__ vt)
{
    __shared__ __align__(16) char smem[49152];   // 3 x (8KB A + 8KB B)
    int bid = (blockIdx.x & 7) * 432 + (blockIdx.x >> 3);   // XCD swizzle
    int brow = (bid / 6) * 128, bcol = (bid % 6) * 128;
    int tid = threadIdx.x, lane = tid & 63, wv = tid >> 6;
    int wr = wv >> 1, wc = wv & 1;

    // staging geometry: tile half = 128 rows x 32 bf16 (8KB) = 512 x 16B
    const unsigned short* srcA[2];
    const unsigned short* srcB[2];
    char* dstA[2];
    char* dstB[2];
#pragma unroll
    for (int i = 0; i < 2; ++i) {
        int s = i * 256 + tid;
        int row = s >> 2, c = s & 3;
        int p = brow + row;
        int n = p / 9216; int rem = p - n * 9216;
        int y = rem / 96; int xx = rem - y * 96;
        int csw = (c ^ ((row >> 1) & 3)) << 3;   // swizzled chunk (elements)
        srcA[i] = xp + ((size_t)(n * PH + y) * PH + xx) * CIN + csw;
        srcB[i] = bw + (size_t)(bcol + row) * 1728 + csw;
        int uslot = i * 256 + (tid & ~63);       // wave-uniform
        dstA[i] = smem + uslot * 16;
        dstB[i] = smem + 8192 + uslot * 16;
    }

    // ds_read byte offsets (within one buffer)
    int aoff[4], boff[4];
#pragma unroll
    for (int m = 0; m < 4; ++m) {
        int rowA = wr * 64 + m * 16 + (lane & 15);
        aoff[m] = rowA * 64 + (((lane >> 4) ^ ((rowA >> 1) & 3)) << 4);
        int colB = wc * 64 + m * 16 + (lane & 15);
        boff[m] = 8192 + colB * 64 + (((lane >> 4) ^ ((colB >> 1) & 3)) << 4);
    }

    // prologue: stage tiles 0 and 1 into buffers 0 and 1
#pragma unroll
    for (int i = 0; i < 2; ++i) { gload16(srcA[i], dstA[i]); gload16(srcB[i], dstB[i]); }
    {
        int aO = 32, bO = 32;   // step 1: shift=0, kk=1
#pragma unroll
        for (int i = 0; i < 2; ++i) {
            gload16(srcA[i] + aO, dstA[i] + 16384);
            gload16(srcB[i] + bO, dstB[i] + 16384);
        }
    }

    f32x4 acc[4][4] = {};

    for (int t = 0; t < 53; ++t) {
        asm volatile("s_waitcnt vmcnt(4)" ::: "memory");  // tile t landed; t+1 in flight
        __builtin_amdgcn_s_barrier();
        __builtin_amdgcn_sched_barrier(0);
        if (t < 52) {
            int step = t + 2;
            int nxt = (step % 3) << 14;
            int shift = step / 6, kk = step - shift * 6;
            int aO = ((shift / 3) * PH + (shift % 3)) * CIN + kk * 32;
            int bO = step * 32;
#pragma unroll
            for (int i = 0; i < 2; ++i) {
                gload16(srcA[i] + aO, dstA[i] + nxt);
                gload16(srcB[i] + bO, dstB[i] + nxt);
            }
        }
        int cur = (t % 3) << 14;
        CONV_COMPUTE(cur);
    }
    asm volatile("s_waitcnt vmcnt(0)" ::: "memory");
    __builtin_amdgcn_s_barrier();
    __builtin_amdgcn_sched_barrier(0);
    CONV_COMPUTE(2 << 14);   // t = 53, buffer 2

    // ---- epilogue: sc[row][col^((row&7)<<3)] stride 128 (32KB, XOR-swizzled) ----
    unsigned short* sc = (unsigned short*)smem;
    float bn[4];
#pragma unroll
    for (int n = 0; n < 4; ++n)
        bn[n] = bias[bcol + wc * 64 + n * 16 + (lane & 15)];
#pragma unroll
    for (int m = 0; m < 4; ++m)
#pragma unroll
        for (int n = 0; n < 4; ++n) {
            int col = wc * 64 + n * 16 + (lane & 15);
            int cabs = bcol + col;
            float scale = ((cabs % 192) < 64) ? 0.125f : 1.0f;
#pragma unroll
            for (int j = 0; j < 4; ++j) {
                int row = wr * 64 + m * 16 + (lane >> 4) * 4 + j;
                sc[row * 128 + (col ^ ((row & 7) << 3))] =
                    f2bf((acc[m][n][j] + bn[n]) * scale);
            }
        }
    __syncthreads();
    // qkv store (coalesced 16B)
#pragma unroll
    for (int i = 0; i < 8; ++i) {
        int idx = i * 256 + tid;
        int row = idx >> 4, ch = idx & 15;
        ushort8 pk = *(const ushort8*)(sc + row * 128 + ((ch * 8) ^ ((row & 7) << 3)));
        *(ushort8*)(qkv + (size_t)(brow + row) * COUT + bcol + ch * 8) = pk;
    }
    // fused V^T gather: V channels are a 64-aligned subrange (if present)
    int cstart = -1;
    if (((bcol + 0) % 192) >= 128) cstart = 0;
    if (((bcol + 64) % 192) >= 128) cstart = 64;
    if (cstart >= 0) {
        int head = (bcol + cstart) / 192;
        unsigned short* vth = vt + (size_t)head * 4718592;  // 8*64*9216
        int nblk = brow / 9216;
        int prem = brow - nblk * 9216;
#pragma unroll
        for (int it = 0; it < 4; ++it) {
            int i = it * 256 + tid;
            int d = i & 63, pxb = i >> 6;
            ushort8 pk;
#pragma unroll
            for (int j = 0; j < 8; ++j) {
                int px = pxb * 8 + j;
                pk[j] = sc[px * 128 + ((cstart + d) ^ ((px & 7) << 3))];
            }
            *(ushort8*)(vth + ((size_t)(nblk * 64 + d)) * 9216 + prem + pxb * 8) = pk;
        }
    }
}

// ---- MFMA neighborhood attention (device body) ----
template<int KS>
static __device__ __forceinline__ void na_body(
    const unsigned short* __restrict__ qkv, const unsigned short* __restrict__ vt,
    float* __restrict__ out, int head, int bid)
{
    constexpr int PAD = KS / 2;
    __shared__ float sO[64][97];
    int y = bid % 96, n = bid / 96;
    int tid = threadIdx.x;
    int wv = tid >> 6, lane = tid & 63;
    int g = lane >> 4, pix = lane & 15;
    int x0 = wv * 16;
    int x = x0 + pix;
    int W = x0 - 8;

    size_t qbase = ((size_t)((n * 96 + y) * 96 + x)) * 768 + (size_t)head * 192;
    bf16x8 qf0 = *(const bf16x8*)(qkv + qbase + g * 8);
    bf16x8 qf1 = *(const bf16x8*)(qkv + qbase + 32 + g * 8);

    f32x4 s[KS][2];
#pragma unroll
    for (int di = 0; di < KS; ++di)
#pragma unroll
        for (int kt = 0; kt < 2; ++kt)
#pragma unroll
            for (int r = 0; r < 4; ++r) s[di][kt][r] = -1e30f;

#pragma unroll
    for (int di = 0; di < KS; ++di) {
        int iy = y + di - PAD;
        if (iy < 0 || iy >= 96) continue;
#pragma unroll
        for (int kt = 0; kt < 2; ++kt) {
            int kix_l = W + kt * 16 + pix;
            int ixc = min(max(kix_l, 0), 95);
            size_t kbase = ((size_t)((n * 96 + iy) * 96 + ixc)) * 768
                           + (size_t)head * 192 + 64;
            bf16x8 kf0 = *(const bf16x8*)(qkv + kbase + g * 8);
            bf16x8 kf1 = *(const bf16x8*)(qkv + kbase + 32 + g * 8);
            f32x4 t = {};
            t = __builtin_amdgcn_mfma_f32_16x16x32_bf16(kf0, qf0, t, 0, 0, 0);
            t = __builtin_amdgcn_mfma_f32_16x16x32_bf16(kf1, qf1, t, 0, 0, 0);
#pragma unroll
            for (int r = 0; r < 4; ++r) {
                int kix = W + kt * 16 + g * 4 + r;
                bool valid = ((unsigned)(kix - x + PAD) <= (unsigned)(2 * PAD)) &&
                             ((unsigned)kix < 96u);
                s[di][kt][r] = valid ? t[r] : -1e30f;
            }
        }
    }

    float m = -3.0e38f;
#pragma unroll
    for (int di = 0; di < KS; ++di)
#pragma unroll
        for (int kt = 0; kt < 2; ++kt)
#pragma unroll
            for (int r = 0; r < 4; ++r) m = fmaxf(m, s[di][kt][r]);
    m = fmaxf(m, __shfl_xor(m, 16, 64));
    m = fmaxf(m, __shfl_xor(m, 32, 64));
    float l = 0.f;
#pragma unroll
    for (int di = 0; di < KS; ++di)
#pragma unroll
        for (int kt = 0; kt < 2; ++kt)
#pragma unroll
            for (int r = 0; r < 4; ++r) {
                float p = __expf(s[di][kt][r] - m);
                s[di][kt][r] = p;
                l += p;
            }
    l += __shfl_xor(l, 16, 64);
    l += __shfl_xor(l, 32, 64);

    f32x4 O[4] = {};
    int addrA = ((2 * (g & 1)) * 16 + pix) * 4;
    int addrB = addrA + 64;
    bool kthi = (g >> 1) != 0;
#pragma unroll
    for (int di = 0; di < KS; ++di) {
        int iy = y + di - PAD;
        if (iy < 0 || iy >= 96) continue;
        unsigned int w0[2], w1[2];
#pragma unroll
        for (int kt = 0; kt < 2; ++kt) {
            asm("v_cvt_pk_bf16_f32 %0, %1, %2"
                : "=v"(w0[kt]) : "v"(s[di][kt][0]), "v"(s[di][kt][1]));
            asm("v_cvt_pk_bf16_f32 %0, %1, %2"
                : "=v"(w1[kt]) : "v"(s[di][kt][2]), "v"(s[di][kt][3]));
        }
        int a0 = __builtin_amdgcn_ds_bpermute(addrA, (int)w0[0]);
        int b0 = __builtin_amdgcn_ds_bpermute(addrA, (int)w0[1]);
        int a1 = __builtin_amdgcn_ds_bpermute(addrA, (int)w1[0]);
        int b1 = __builtin_amdgcn_ds_bpermute(addrA, (int)w1[1]);
        int a2 = __builtin_amdgcn_ds_bpermute(addrB, (int)w0[0]);
        int b2 = __builtin_amdgcn_ds_bpermute(addrB, (int)w0[1]);
        int a3 = __builtin_amdgcn_ds_bpermute(addrB, (int)w1[0]);
        int b3 = __builtin_amdgcn_ds_bpermute(addrB, (int)w1[1]);
        union { int u[4]; bf16x8 v; } pa;
        pa.u[0] = kthi ? b0 : a0;
        pa.u[1] = kthi ? b1 : a1;
        pa.u[2] = kthi ? b2 : a2;
        pa.u[3] = kthi ? b3 : a3;
#pragma unroll
        for (int dc = 0; dc < 4; ++dc) {
            long voff = ((long)((n * 64 + dc * 16 + pix) * 96 + iy)) * 96 + (W + g * 8);
            bf16x8 vf = *(const bf16x8*)(vt + voff);
            O[dc] = __builtin_amdgcn_mfma_f32_16x16x32_bf16(pa.v, vf, O[dc], 0, 0, 0);
        }
    }

    float linv = 1.0f / l;
    float linvj[4];
#pragma unroll
    for (int j = 0; j < 4; ++j)
        linvj[j] = __uint_as_float((unsigned)__builtin_amdgcn_ds_bpermute(
            (4 * g + j) * 4, (int)__float_as_uint(linv)));
#pragma unroll
    for (int dc = 0; dc < 4; ++dc)
#pragma unroll
        for (int j = 0; j < 4; ++j)
            sO[dc * 16 + pix][x0 + g * 4 + j] = O[dc][j] * linvj[j];
    __syncthreads();
    for (int i = tid; i < 1536; i += 384) {
        int d = i / 24, xq = i % 24;
        float4 v4 = { sO[d][xq * 4], sO[d][xq * 4 + 1],
                      sO[d][xq * 4 + 2], sO[d][xq * 4 + 3] };
        *(float4*)(out + ((size_t)(head * 8 + n) * 64 + d) * 9216
                   + y * 96 + xq * 4) = v4;
    }
}

// all 4 heads in one dispatch: head = blockIdx.x / 768
__global__ __launch_bounds__(384, 3) void na_mfma_all(
    const unsigned short* __restrict__ qkv, const unsigned short* __restrict__ vtb,
    const unsigned short* __restrict__ vtws, float* __restrict__ out)
{
    int head = blockIdx.x / 768;
    int bid = blockIdx.x % 768;
    switch (head) {
        case 0: na_body<3>(qkv, vtb,               out, 0, bid); break;
        case 1: na_body<5>(qkv, vtb + 4718592,     out, 1, bid); break;
        case 2: na_body<7>(qkv, vtb + 2 * 4718592, out, 2, bid); break;
        default: na_body<9>(qkv, vtws,             out, 3, bid); break;
    }
}

extern "C" void kernel_launch(void* const* d_in, const int* in_sizes, int n_in,
                              void* d_out, int out_size, void* d_ws, size_t ws_size,
                              hipStream_t stream) {
    const float* x  = (const float*)d_in[0];
    const float* w  = (const float*)d_in[1];
    const float* b  = (const float*)d_in[2];
    float* out = (float*)d_out;

    unsigned short* qkv  = (unsigned short*)d_ws;                       // 113246208 B
    unsigned short* xpad = (unsigned short*)((char*)d_ws + 113246208);  // 29503488 B
    unsigned short* bw   = (unsigned short*)((char*)d_ws + 142749696);  // 2654208 B

    // vt (4 heads x 9.44MB bf16) lives in d_out's upper half (free until NA runs)
    unsigned short* vtb  = (unsigned short*)((char*)d_out + 37748736);
    // head-3's vt copy goes to the dead xpad region (free after conv)
    unsigned short* vtws = xpad;

    hipMemsetAsync(xpad, 0, 29503488, stream);
    pack_x_kernel<<<NB * NH * 6, 256, 0, stream>>>(x, xpad);
    pack_w_kernel<<<COUT, 256, 0, stream>>>(w, bw);
    conv_gemm_kernel<<<3456, 256, 0, stream>>>(xpad, bw, b, qkv, vtb);

    hipMemcpyAsync(vtws, vtb + (size_t)3 * 4718592, 9437184,
                   hipMemcpyDeviceToDevice, stream);

    na_mfma_all<<<4 * 768, 384, 0, stream>>>(qkv, vtb, vtws, out);
}

// Round 6
// 403.278 us; speedup vs baseline: 9.6552x; 1.0034x over previous
//
#include <hip/hip_runtime.h>
#include <hip/hip_bf16.h>

#define NH 96
#define NW 96
#define NB 8
#define CIN 192
#define COUT 768   // 4 heads * 3 * 64
#define PH 98      // padded spatial dim

typedef __attribute__((ext_vector_type(8))) unsigned short ushort8;
typedef __attribute__((ext_vector_type(8))) short bf16x8;
typedef __attribute__((ext_vector_type(4))) float f32x4;

static __device__ __forceinline__ unsigned short f2bf(float f) {
    unsigned int u = __float_as_uint(f);
    return (unsigned short)((u + 0x7fffu + ((u >> 16) & 1u)) >> 16);
}

typedef const __attribute__((address_space(1))) unsigned int gu32;
typedef __attribute__((address_space(3))) unsigned int lu32;
static __device__ __forceinline__ void gload16(const void* g, void* l) {
    __builtin_amdgcn_global_load_lds((gu32*)g, (lu32*)l, 16, 0, 0);
}

// ---- pack x: NCHW fp32 -> zero-padded NHWC bf16 [8][98][98][192] ----
__global__ __launch_bounds__(256) void pack_x_kernel(
    const float* __restrict__ x, unsigned short* __restrict__ xp)
{
    __shared__ float tile[32][97];
    int bid = blockIdx.x;
    int ct = bid % 6; int y = (bid / 6) % NH; int n = bid / (6 * NH);
    int tid = threadIdx.x;
    int c0 = ct * 32;
    for (int i = tid; i < 32 * 96; i += 256) {
        int c = i / 96, xx = i % 96;
        tile[c][xx] = x[(((size_t)n * CIN + c0 + c) * NH + y) * NW + xx];
    }
    __syncthreads();
    for (int i = tid; i < 96 * 4; i += 256) {
        int xx = i >> 2, ch = i & 3;
        ushort8 pk;
#pragma unroll
        for (int j = 0; j < 8; ++j) pk[j] = f2bf(tile[ch * 8 + j][xx]);
        *(ushort8*)(xp + ((size_t)(n * PH + y + 1) * PH + xx + 1) * CIN + c0 + ch * 8) = pk;
    }
}

// ---- pack w: [co][ci][3][3] fp32 -> [co][(di*3+dj)*192+ci] bf16 ----
__global__ __launch_bounds__(256) void pack_w_kernel(
    const float* __restrict__ w, unsigned short* __restrict__ bw)
{
    __shared__ float ls[1728];
    int co = blockIdx.x; int tid = threadIdx.x;
    for (int i = tid; i < 1728; i += 256) ls[i] = w[(size_t)co * 1728 + i];
    __syncthreads();
    for (int i = tid; i < 1728; i += 256) {
        int sh = i / 192, ci = i % 192;
        bw[(size_t)co * 1728 + i] = f2bf(ls[ci * 9 + sh]);
    }
}

// ---- implicit-GEMM conv: M=73728, N=768, K=1728 ----
// 128x128 tile, BK=32, QUAD-buffered LDS (64KB), stage 3 tiles ahead with
// counted vmcnt(4); fragment registers double-buffered so MFMA(t) runs on
// regs loaded during step t-1 while ds_read prefetches t+1. XCD swizzle.
// Q pre-scaled by 0.125. Epilogue fuses V^T pack.
#define STAGE(S, BUF)                                                          \
    {                                                                          \
        int shift_ = (S) / 6, kk_ = (S) - shift_ * 6;                          \
        int aO_ = ((shift_ / 3) * PH + (shift_ % 3)) * CIN + kk_ * 32;         \
        int bO_ = (S) * 32;                                                    \
        _Pragma("unroll")                                                      \
        for (int i_ = 0; i_ < 2; ++i_) {                                       \
            gload16(srcA[i_] + aO_, dstA[i_] + (BUF));                         \
            gload16(srcB[i_] + bO_, dstB[i_] + (BUF));                         \
        }                                                                      \
    }

#define LOADFRAGS(AF, BF, CUR)                                                 \
    {                                                                          \
        _Pragma("unroll")                                                      \
        for (int m_ = 0; m_ < 4; ++m_)                                         \
            AF[m_] = *(const bf16x8*)(smem + (CUR) + aoff[m_]);                \
        _Pragma("unroll")                                                      \
        for (int n_ = 0; n_ < 4; ++n_)                                         \
            BF[n_] = *(const bf16x8*)(smem + (CUR) + boff[n_]);                \
    }

#define DOMFMA(AF, BF)                                                         \
    {                                                                          \
        __builtin_amdgcn_s_setprio(1);                                         \
        _Pragma("unroll")                                                      \
        for (int m_ = 0; m_ < 4; ++m_)                                         \
            _Pragma("unroll")                                                  \
            for (int n_ = 0; n_ < 4; ++n_)                                     \
                acc[m_][n_] = __builtin_amdgcn_mfma_f32_16x16x32_bf16(         \
                    AF[m_], BF[n_], acc[m_][n_], 0, 0, 0);                     \
        __builtin_amdgcn_s_setprio(0);                                         \
    }

__global__ __launch_bounds__(256, 2) void conv_gemm_kernel(
    const unsigned short* __restrict__ xp, const unsigned short* __restrict__ bw,
    const float* __restrict__ bias, unsigned short* __restrict__ qkv,
    unsigned short* __restrict__ vt)
{
    __shared__ __align__(16) char smem[65536];   // 4 x (8KB A + 8KB B)
    int bid = (blockIdx.x & 7) * 432 + (blockIdx.x >> 3);   // XCD swizzle
    int brow = (bid / 6) * 128, bcol = (bid % 6) * 128;
    int tid = threadIdx.x, lane = tid & 63, wv = tid >> 6;
    int wr = wv >> 1, wc = wv & 1;

    // staging geometry: tile half = 128 rows x 32 bf16 (8KB) = 512 x 16B
    const unsigned short* srcA[2];
    const unsigned short* srcB[2];
    char* dstA[2];
    char* dstB[2];
#pragma unroll
    for (int i = 0; i < 2; ++i) {
        int s = i * 256 + tid;
        int row = s >> 2, c = s & 3;
        int p = brow + row;
        int n = p / 9216; int rem = p - n * 9216;
        int y = rem / 96; int xx = rem - y * 96;
        int csw = (c ^ ((row >> 1) & 3)) << 3;   // swizzled chunk (elements)
        srcA[i] = xp + ((size_t)(n * PH + y) * PH + xx) * CIN + csw;
        srcB[i] = bw + (size_t)(bcol + row) * 1728 + csw;
        int uslot = i * 256 + (tid & ~63);       // wave-uniform
        dstA[i] = smem + uslot * 16;
        dstB[i] = smem + 8192 + uslot * 16;
    }

    // ds_read byte offsets (within one buffer)
    int aoff[4], boff[4];
#pragma unroll
    for (int m = 0; m < 4; ++m) {
        int rowA = wr * 64 + m * 16 + (lane & 15);
        aoff[m] = rowA * 64 + (((lane >> 4) ^ ((rowA >> 1) & 3)) << 4);
        int colB = wc * 64 + m * 16 + (lane & 15);
        boff[m] = 8192 + colB * 64 + (((lane >> 4) ^ ((colB >> 1) & 3)) << 4);
    }

    // prologue: stage tiles 0,1,2 into buffers 0,1,2
    STAGE(0, 0);
    STAGE(1, 16384);
    STAGE(2, 32768);
    asm volatile("s_waitcnt vmcnt(8)" ::: "memory");   // tile 0 landed
    __builtin_amdgcn_s_barrier();

    f32x4 acc[4][4] = {};
    bf16x8 afA[4], bfA[4], afB[4], bfB[4];
    LOADFRAGS(afA, bfA, 0);                            // frags for tile 0

    for (int u = 0; u < 26; ++u) {
        int t0 = 2 * u;
        // step t0: MFMA on afA (tile t0), prefetch frags of t0+1
        asm volatile("s_waitcnt vmcnt(4)" ::: "memory");  // tile t0+1 landed
        __builtin_amdgcn_s_barrier();
        if (t0 < 51) STAGE(t0 + 3, ((t0 + 3) & 3) << 14);
        __builtin_amdgcn_sched_barrier(0);
        DOMFMA(afA, bfA);
        LOADFRAGS(afB, bfB, ((t0 + 1) & 3) << 14);
        // step t0+1
        asm volatile("s_waitcnt vmcnt(4)" ::: "memory");  // tile t0+2 landed
        __builtin_amdgcn_s_barrier();
        if (t0 + 1 < 51) STAGE(t0 + 4, ((t0 + 4) & 3) << 14);
        __builtin_amdgcn_sched_barrier(0);
        DOMFMA(afB, bfB);
        LOADFRAGS(afA, bfA, ((t0 + 2) & 3) << 14);
    }
    // u loop handled t=0..51; afA holds tile 52's fragments
    asm volatile("s_waitcnt vmcnt(0)" ::: "memory");      // tile 53 landed
    __builtin_amdgcn_s_barrier();
    DOMFMA(afA, bfA);                                     // tile 52
    LOADFRAGS(afB, bfB, (53 & 3) << 14);
    DOMFMA(afB, bfB);                                     // tile 53

    // ---- epilogue: sc[row][col^((row&7)<<3)] stride 128 (32KB, XOR-swizzled) ----
    __builtin_amdgcn_s_barrier();
    unsigned short* sc = (unsigned short*)smem;
    float bn[4];
#pragma unroll
    for (int n = 0; n < 4; ++n)
        bn[n] = bias[bcol + wc * 64 + n * 16 + (lane & 15)];
#pragma unroll
    for (int m = 0; m < 4; ++m)
#pragma unroll
        for (int n = 0; n < 4; ++n) {
            int col = wc * 64 + n * 16 + (lane & 15);
            int cabs = bcol + col;
            float scale = ((cabs % 192) < 64) ? 0.125f : 1.0f;
#pragma unroll
            for (int j = 0; j < 4; ++j) {
                int row = wr * 64 + m * 16 + (lane >> 4) * 4 + j;
                sc[row * 128 + (col ^ ((row & 7) << 3))] =
                    f2bf((acc[m][n][j] + bn[n]) * scale);
            }
        }
    __syncthreads();
    // qkv store (coalesced 16B)
#pragma unroll
    for (int i = 0; i < 8; ++i) {
        int idx = i * 256 + tid;
        int row = idx >> 4, ch = idx & 15;
        ushort8 pk = *(const ushort8*)(sc + row * 128 + ((ch * 8) ^ ((row & 7) << 3)));
        *(ushort8*)(qkv + (size_t)(brow + row) * COUT + bcol + ch * 8) = pk;
    }
    // fused V^T gather: V channels are a 64-aligned subrange (if present)
    int cstart = -1;
    if (((bcol + 0) % 192) >= 128) cstart = 0;
    if (((bcol + 64) % 192) >= 128) cstart = 64;
    if (cstart >= 0) {
        int head = (bcol + cstart) / 192;
        unsigned short* vth = vt + (size_t)head * 4718592;  // 8*64*9216
        int nblk = brow / 9216;
        int prem = brow - nblk * 9216;
#pragma unroll
        for (int it = 0; it < 4; ++it) {
            int i = it * 256 + tid;
            int d = i & 63, pxb = i >> 6;
            ushort8 pk;
#pragma unroll
            for (int j = 0; j < 8; ++j) {
                int px = pxb * 8 + j;
                pk[j] = sc[px * 128 + ((cstart + d) ^ ((px & 7) << 3))];
            }
            *(ushort8*)(vth + ((size_t)(nblk * 64 + d)) * 9216 + prem + pxb * 8) = pk;
        }
    }
}

// ---- MFMA neighborhood attention (device body) ----
template<int KS>
static __device__ __forceinline__ void na_body(
    const unsigned short* __restrict__ qkv, const unsigned short* __restrict__ vt,
    float* __restrict__ out, int head, int bid)
{
    constexpr int PAD = KS / 2;
    __shared__ float sO[64][97];
    int y = bid % 96, n = bid / 96;
    int tid = threadIdx.x;
    int wv = tid >> 6, lane = tid & 63;
    int g = lane >> 4, pix = lane & 15;
    int x0 = wv * 16;
    int x = x0 + pix;
    int W = x0 - 8;

    size_t qbase = ((size_t)((n * 96 + y) * 96 + x)) * 768 + (size_t)head * 192;
    bf16x8 qf0 = *(const bf16x8*)(qkv + qbase + g * 8);
    bf16x8 qf1 = *(const bf16x8*)(qkv + qbase + 32 + g * 8);

    f32x4 s[KS][2];
#pragma unroll
    for (int di = 0; di < KS; ++di)
#pragma unroll
        for (int kt = 0; kt < 2; ++kt)
#pragma unroll
            for (int r = 0; r < 4; ++r) s[di][kt][r] = -1e30f;

#pragma unroll
    for (int di = 0; di < KS; ++di) {
        int iy = y + di - PAD;
        if (iy < 0 || iy >= 96) continue;
#pragma unroll
        for (int kt = 0; kt < 2; ++kt) {
            int kix_l = W + kt * 16 + pix;
            int ixc = min(max(kix_l, 0), 95);
            size_t kbase = ((size_t)((n * 96 + iy) * 96 + ixc)) * 768
                           + (size_t)head * 192 + 64;
            bf16x8 kf0 = *(const bf16x8*)(qkv + kbase + g * 8);
            bf16x8 kf1 = *(const bf16x8*)(qkv + kbase + 32 + g * 8);
            f32x4 t = {};
            t = __builtin_amdgcn_mfma_f32_16x16x32_bf16(kf0, qf0, t, 0, 0, 0);
            t = __builtin_amdgcn_mfma_f32_16x16x32_bf16(kf1, qf1, t, 0, 0, 0);
#pragma unroll
            for (int r = 0; r < 4; ++r) {
                int kix = W + kt * 16 + g * 4 + r;
                bool valid = ((unsigned)(kix - x + PAD) <= (unsigned)(2 * PAD)) &&
                             ((unsigned)kix < 96u);
                s[di][kt][r] = valid ? t[r] : -1e30f;
            }
        }
    }

    float m = -3.0e38f;
#pragma unroll
    for (int di = 0; di < KS; ++di)
#pragma unroll
        for (int kt = 0; kt < 2; ++kt)
#pragma unroll
            for (int r = 0; r < 4; ++r) m = fmaxf(m, s[di][kt][r]);
    m = fmaxf(m, __shfl_xor(m, 16, 64));
    m = fmaxf(m, __shfl_xor(m, 32, 64));
    float l = 0.f;
#pragma unroll
    for (int di = 0; di < KS; ++di)
#pragma unroll
        for (int kt = 0; kt < 2; ++kt)
#pragma unroll
            for (int r = 0; r < 4; ++r) {
                float p = __expf(s[di][kt][r] - m);
                s[di][kt][r] = p;
                l += p;
            }
    l += __shfl_xor(l, 16, 64);
    l += __shfl_xor(l, 32, 64);

    f32x4 O[4] = {};
    int addrA = ((2 * (g & 1)) * 16 + pix) * 4;
    int addrB = addrA + 64;
    bool kthi = (g >> 1) != 0;
#pragma unroll
    for (int di = 0; di < KS; ++di) {
        int iy = y + di - PAD;
        if (iy < 0 || iy >= 96) continue;
        unsigned int w0[2], w1[2];
#pragma unroll
        for (int kt = 0; kt < 2; ++kt) {
            asm("v_cvt_pk_bf16_f32 %0, %1, %2"
                : "=v"(w0[kt]) : "v"(s[di][kt][0]), "v"(s[di][kt][1]));
            asm("v_cvt_pk_bf16_f32 %0, %1, %2"
                : "=v"(w1[kt]) : "v"(s[di][kt][2]), "v"(s[di][kt][3]));
        }
        int a0 = __builtin_amdgcn_ds_bpermute(addrA, (int)w0[0]);
        int b0 = __builtin_amdgcn_ds_bpermute(addrA, (int)w0[1]);
        int a1 = __builtin_amdgcn_ds_bpermute(addrA, (int)w1[0]);
        int b1 = __builtin_amdgcn_ds_bpermute(addrA, (int)w1[1]);
        int a2 = __builtin_amdgcn_ds_bpermute(addrB, (int)w0[0]);
        int b2 = __builtin_amdgcn_ds_bpermute(addrB, (int)w0[1]);
        int a3 = __builtin_amdgcn_ds_bpermute(addrB, (int)w1[0]);
        int b3 = __builtin_amdgcn_ds_bpermute(addrB, (int)w1[1]);
        union { int u[4]; bf16x8 v; } pa;
        pa.u[0] = kthi ? b0 : a0;
        pa.u[1] = kthi ? b1 : a1;
        pa.u[2] = kthi ? b2 : a2;
        pa.u[3] = kthi ? b3 : a3;
#pragma unroll
        for (int dc = 0; dc < 4; ++dc) {
            long voff = ((long)((n * 64 + dc * 16 + pix) * 96 + iy)) * 96 + (W + g * 8);
            bf16x8 vf = *(const bf16x8*)(vt + voff);
            O[dc] = __builtin_amdgcn_mfma_f32_16x16x32_bf16(pa.v, vf, O[dc], 0, 0, 0);
        }
    }

    float linv = 1.0f / l;
    float linvj[4];
#pragma unroll
    for (int j = 0; j < 4; ++j)
        linvj[j] = __uint_as_float((unsigned)__builtin_amdgcn_ds_bpermute(
            (4 * g + j) * 4, (int)__float_as_uint(linv)));
#pragma unroll
    for (int dc = 0; dc < 4; ++dc)
#pragma unroll
        for (int j = 0; j < 4; ++j)
            sO[dc * 16 + pix][x0 + g * 4 + j] = O[dc][j] * linvj[j];
    __syncthreads();
    for (int i = tid; i < 1536; i += 384) {
        int d = i / 24, xq = i % 24;
        float4 v4 = { sO[d][xq * 4], sO[d][xq * 4 + 1],
                      sO[d][xq * 4 + 2], sO[d][xq * 4 + 3] };
        *(float4*)(out + ((size_t)(head * 8 + n) * 64 + d) * 9216
                   + y * 96 + xq * 4) = v4;
    }
}

// all 4 heads in one dispatch: head = blockIdx.x / 768
__global__ __launch_bounds__(384, 3) void na_mfma_all(
    const unsigned short* __restrict__ qkv, const unsigned short* __restrict__ vtb,
    const unsigned short* __restrict__ vtws, float* __restrict__ out)
{
    int head = blockIdx.x / 768;
    int bid = blockIdx.x % 768;
    switch (head) {
        case 0: na_body<3>(qkv, vtb,               out, 0, bid); break;
        case 1: na_body<5>(qkv, vtb + 4718592,     out, 1, bid); break;
        case 2: na_body<7>(qkv, vtb + 2 * 4718592, out, 2, bid); break;
        default: na_body<9>(qkv, vtws,             out, 3, bid); break;
    }
}

extern "C" void kernel_launch(void* const* d_in, const int* in_sizes, int n_in,
                              void* d_out, int out_size, void* d_ws, size_t ws_size,
                              hipStream_t stream) {
    const float* x  = (const float*)d_in[0];
    const float* w  = (const float*)d_in[1];
    const float* b  = (const float*)d_in[2];
    float* out = (float*)d_out;

    unsigned short* qkv  = (unsigned short*)d_ws;                       // 113246208 B
    unsigned short* xpad = (unsigned short*)((char*)d_ws + 113246208);  // 29503488 B
    unsigned short* bw   = (unsigned short*)((char*)d_ws + 142749696);  // 2654208 B

    // vt (4 heads x 9.44MB bf16) lives in d_out's upper half (free until NA runs)
    unsigned short* vtb  = (unsigned short*)((char*)d_out + 37748736);
    // head-3's vt copy goes to the dead xpad region (free after conv)
    unsigned short* vtws = xpad;

    hipMemsetAsync(xpad, 0, 29503488, stream);
    pack_x_kernel<<<NB * NH * 6, 256, 0, stream>>>(x, xpad);
    pack_w_kernel<<<COUT, 256, 0, stream>>>(w, bw);
    conv_gemm_kernel<<<3456, 256, 0, stream>>>(xpad, bw, b, qkv, vtb);

    hipMemcpyAsync(vtws, vtb + (size_t)3 * 4718592, 9437184,
                   hipMemcpyDeviceToDevice, stream);

    na_mfma_all<<<4 * 768, 384, 0, stream>>>(qkv, vtb, vtws, out);
}

// Round 7
// 373.534 us; speedup vs baseline: 10.4240x; 1.0796x over previous
//
#include <hip/hip_runtime.h>
#include <hip/hip_bf16.h>

#define NH 96
#define NW 96
#define NB 8
#define CIN 192
#define COUT 768   // 4 heads * 3 * 64
#define PH 98      // padded spatial dim

typedef __attribute__((ext_vector_type(8))) unsigned short ushort8;
typedef __attribute__((ext_vector_type(8))) short bf16x8;
typedef __attribute__((ext_vector_type(4))) float f32x4;

static __device__ __forceinline__ unsigned short f2bf(float f) {
    unsigned int u = __float_as_uint(f);
    return (unsigned short)((u + 0x7fffu + ((u >> 16) & 1u)) >> 16);
}

typedef const __attribute__((address_space(1))) unsigned int gu32;
typedef __attribute__((address_space(3))) unsigned int lu32;
static __device__ __forceinline__ void gload16(const void* g, void* l) {
    __builtin_amdgcn_global_load_lds((gu32*)g, (lu32*)l, 16, 0, 0);
}

// ---- pack x: NCHW fp32 -> zero-padded NHWC bf16 [8][98][98][192] ----
__global__ __launch_bounds__(256) void pack_x_kernel(
    const float* __restrict__ x, unsigned short* __restrict__ xp)
{
    __shared__ float tile[32][97];
    int bid = blockIdx.x;
    int ct = bid % 6; int y = (bid / 6) % NH; int n = bid / (6 * NH);
    int tid = threadIdx.x;
    int c0 = ct * 32;
    for (int i = tid; i < 32 * 96; i += 256) {
        int c = i / 96, xx = i % 96;
        tile[c][xx] = x[(((size_t)n * CIN + c0 + c) * NH + y) * NW + xx];
    }
    __syncthreads();
    for (int i = tid; i < 96 * 4; i += 256) {
        int xx = i >> 2, ch = i & 3;
        ushort8 pk;
#pragma unroll
        for (int j = 0; j < 8; ++j) pk[j] = f2bf(tile[ch * 8 + j][xx]);
        *(ushort8*)(xp + ((size_t)(n * PH + y + 1) * PH + xx + 1) * CIN + c0 + ch * 8) = pk;
    }
}

// ---- pack w: [co][ci][3][3] fp32 -> [co][(di*3+dj)*192+ci] bf16 ----
__global__ __launch_bounds__(256) void pack_w_kernel(
    const float* __restrict__ w, unsigned short* __restrict__ bw)
{
    __shared__ float ls[1728];
    int co = blockIdx.x; int tid = threadIdx.x;
    for (int i = tid; i < 1728; i += 256) ls[i] = w[(size_t)co * 1728 + i];
    __syncthreads();
    for (int i = tid; i < 1728; i += 256) {
        int sh = i / 192, ci = i % 192;
        bw[(size_t)co * 1728 + i] = f2bf(ls[ci * 9 + sh]);
    }
}

// ---- implicit-GEMM conv: M=73728, N=768, K=1728 ----
// 256x256 tile, BK=32, 8 waves (2Mx4N), QUAD-buffered LDS (128KB), stage 3
// tiles ahead, counted vmcnt(8) (never drains in-loop). XCD swizzle.
// Writes Q/K (stride 512, Q pre-scaled 0.125) and V^T (fused pack).
#define STAGE(S, BUF)                                                          \
    {                                                                          \
        int shift_ = (S) / 6, kk_ = (S) - shift_ * 6;                          \
        int aO_ = ((shift_ / 3) * PH + (shift_ % 3)) * CIN + kk_ * 32;         \
        int bO_ = (S) * 32;                                                    \
        _Pragma("unroll")                                                      \
        for (int i_ = 0; i_ < 2; ++i_) {                                       \
            gload16(srcA[i_] + aO_, dstA[i_] + (BUF));                         \
            gload16(srcB[i_] + bO_, dstB[i_] + (BUF));                         \
        }                                                                      \
    }

#define COMPUTE(CUR)                                                           \
    {                                                                          \
        bf16x8 af[8], bf[4];                                                   \
        _Pragma("unroll")                                                      \
        for (int m_ = 0; m_ < 8; ++m_)                                         \
            af[m_] = *(const bf16x8*)(smem + (CUR) + aoff[m_]);                \
        _Pragma("unroll")                                                      \
        for (int n_ = 0; n_ < 4; ++n_)                                         \
            bf[n_] = *(const bf16x8*)(smem + (CUR) + boff[n_]);                \
        __builtin_amdgcn_s_setprio(1);                                         \
        _Pragma("unroll")                                                      \
        for (int m_ = 0; m_ < 8; ++m_)                                         \
            _Pragma("unroll")                                                  \
            for (int n_ = 0; n_ < 4; ++n_)                                     \
                acc[m_][n_] = __builtin_amdgcn_mfma_f32_16x16x32_bf16(         \
                    af[m_], bf[n_], acc[m_][n_], 0, 0, 0);                     \
        __builtin_amdgcn_s_setprio(0);                                         \
    }

__global__ __launch_bounds__(512, 2) void conv_gemm_kernel(
    const unsigned short* __restrict__ xp, const unsigned short* __restrict__ bw,
    const float* __restrict__ bias, unsigned short* __restrict__ qkq,
    unsigned short* __restrict__ vt)
{
    __shared__ __align__(16) char smem[131072];   // 4 x (16KB A + 16KB B)
    int bid = (blockIdx.x & 7) * 108 + (blockIdx.x >> 3);   // XCD swizzle (864%8==0)
    int brow = (bid / 3) * 256, bcol = (bid % 3) * 256;
    int tid = threadIdx.x, lane = tid & 63, wid = tid >> 6;
    int wm = wid >> 2, wn = wid & 3;

    // staging: per K-step each thread issues 2 A-loads + 2 B-loads (16B each)
    const unsigned short* srcA[2];
    const unsigned short* srcB[2];
    char* dstA[2];
    char* dstB[2];
#pragma unroll
    for (int i = 0; i < 2; ++i) {
        int s = i * 512 + tid;
        int row = s >> 2, c = s & 3;          // 256 rows x 4 chunks of 16B
        int p = brow + row;
        int n = p / 9216; int rem = p - n * 9216;
        int y = rem / 96; int xx = rem - y * 96;
        int csw = (c ^ ((row >> 1) & 3)) << 3;   // swizzled chunk (elements)
        srcA[i] = xp + ((size_t)(n * PH + y) * PH + xx) * CIN + csw;
        srcB[i] = bw + (size_t)(bcol + row) * 1728 + csw;
        int uslot = i * 512 + (tid & ~63);       // wave-uniform
        dstA[i] = smem + uslot * 16;
        dstB[i] = smem + 16384 + uslot * 16;
    }

    // ds_read byte offsets (within one buffer)
    int aoff[8], boff[4];
#pragma unroll
    for (int m = 0; m < 8; ++m) {
        int rowA = wm * 128 + m * 16 + (lane & 15);
        aoff[m] = rowA * 64 + (((lane >> 4) ^ ((rowA >> 1) & 3)) << 4);
    }
#pragma unroll
    for (int n = 0; n < 4; ++n) {
        int colB = wn * 64 + n * 16 + (lane & 15);
        boff[n] = 16384 + colB * 64 + (((lane >> 4) ^ ((colB >> 1) & 3)) << 4);
    }

    // prologue: stage tiles 0,1,2 into buffers 0,1,2
    STAGE(0, 0);
    STAGE(1, 32768);
    STAGE(2, 65536);

    f32x4 acc[8][4] = {};

    for (int t = 0; t < 52; ++t) {
        asm volatile("s_waitcnt vmcnt(8)" ::: "memory");  // tile t landed; t+1,t+2 in flight
        __builtin_amdgcn_s_barrier();
        if (t < 51) STAGE(t + 3, ((t + 3) & 3) << 15);
        __builtin_amdgcn_sched_barrier(0);
        COMPUTE((t & 3) << 15);
    }
    // t = 52
    asm volatile("s_waitcnt vmcnt(4)" ::: "memory");
    __builtin_amdgcn_s_barrier();
    COMPUTE((52 & 3) << 15);
    // t = 53
    asm volatile("s_waitcnt vmcnt(0)" ::: "memory");
    __builtin_amdgcn_s_barrier();
    COMPUTE((53 & 3) << 15);

    // ---- epilogue: sc[row][col^((row&7)<<3)] stride 256 (128KB, swizzled) ----
    __syncthreads();
    unsigned short* sc = (unsigned short*)smem;
    float bn[4];
#pragma unroll
    for (int n = 0; n < 4; ++n)
        bn[n] = bias[bcol + wn * 64 + n * 16 + (lane & 15)];
#pragma unroll
    for (int m = 0; m < 8; ++m)
#pragma unroll
        for (int n = 0; n < 4; ++n) {
            int col = wn * 64 + n * 16 + (lane & 15);
            int cabs = bcol + col;
            float scale = ((cabs % 192) < 64) ? 0.125f : 1.0f;
#pragma unroll
            for (int j = 0; j < 4; ++j) {
                int row = wm * 128 + m * 16 + (lane >> 4) * 4 + j;
                sc[row * 256 + (col ^ ((row & 7) << 3))] =
                    f2bf((acc[m][n][j] + bn[n]) * scale);
            }
        }
    __syncthreads();
    // Q/K store: channel c -> qkq[(c/192)*128 + c%192] if c%192 < 128
#pragma unroll
    for (int i = 0; i < 16; ++i) {
        int idx = i * 512 + tid;
        int row = idx >> 5, ch = idx & 31;
        int c0 = bcol + ch * 8;
        int r192 = c0 % 192;
        if (r192 < 128) {
            ushort8 pk = *(const ushort8*)(sc + row * 256 + ((ch * 8) ^ ((row & 7) << 3)));
            *(ushort8*)(qkq + (size_t)(brow + row) * 512 + (c0 / 192) * 128 + r192) = pk;
        }
    }
    // fused V^T gather (heads whose V-range lies in this col-tile)
    int nblk = brow / 9216;
    int prem = brow - nblk * 9216;
#pragma unroll
    for (int h = 0; h < 4; ++h) {
        int lc = h * 192 + 128 - bcol;
        if (lc < 0 || lc > 192) continue;
        unsigned short* vth = vt + (size_t)h * 4718592;  // 8*64*9216
#pragma unroll
        for (int it = 0; it < 4; ++it) {
            int i = it * 512 + tid;
            int d = i & 63, pxb = i >> 6;
            ushort8 pk;
#pragma unroll
            for (int j = 0; j < 8; ++j) {
                int px = pxb * 8 + j;
                pk[j] = sc[px * 256 + ((lc + d) ^ ((px & 7) << 3))];
            }
            *(ushort8*)(vth + ((size_t)(nblk * 64 + d)) * 9216 + prem + pxb * 8) = pk;
        }
    }
}

// ---- MFMA neighborhood attention (device body); qkq stride 512 ----
template<int KS>
static __device__ __forceinline__ void na_body(
    const unsigned short* __restrict__ qkq, const unsigned short* __restrict__ vt,
    float* __restrict__ out, int head, int bid)
{
    constexpr int PAD = KS / 2;
    __shared__ float sO[64][97];
    int y = bid % 96, n = bid / 96;
    int tid = threadIdx.x;
    int wv = tid >> 6, lane = tid & 63;
    int g = lane >> 4, pix = lane & 15;
    int x0 = wv * 16;
    int x = x0 + pix;
    int W = x0 - 8;

    size_t qbase = ((size_t)((n * 96 + y) * 96 + x)) * 512 + (size_t)head * 128;
    bf16x8 qf0 = *(const bf16x8*)(qkq + qbase + g * 8);
    bf16x8 qf1 = *(const bf16x8*)(qkq + qbase + 32 + g * 8);

    f32x4 s[KS][2];
#pragma unroll
    for (int di = 0; di < KS; ++di)
#pragma unroll
        for (int kt = 0; kt < 2; ++kt)
#pragma unroll
            for (int r = 0; r < 4; ++r) s[di][kt][r] = -1e30f;

#pragma unroll
    for (int di = 0; di < KS; ++di) {
        int iy = y + di - PAD;
        if (iy < 0 || iy >= 96) continue;
#pragma unroll
        for (int kt = 0; kt < 2; ++kt) {
            int kix_l = W + kt * 16 + pix;
            int ixc = min(max(kix_l, 0), 95);
            size_t kbase = ((size_t)((n * 96 + iy) * 96 + ixc)) * 512
                           + (size_t)head * 128 + 64;
            bf16x8 kf0 = *(const bf16x8*)(qkq + kbase + g * 8);
            bf16x8 kf1 = *(const bf16x8*)(qkq + kbase + 32 + g * 8);
            f32x4 t = {};
            t = __builtin_amdgcn_mfma_f32_16x16x32_bf16(kf0, qf0, t, 0, 0, 0);
            t = __builtin_amdgcn_mfma_f32_16x16x32_bf16(kf1, qf1, t, 0, 0, 0);
#pragma unroll
            for (int r = 0; r < 4; ++r) {
                int kix = W + kt * 16 + g * 4 + r;
                bool valid = ((unsigned)(kix - x + PAD) <= (unsigned)(2 * PAD)) &&
                             ((unsigned)kix < 96u);
                s[di][kt][r] = valid ? t[r] : -1e30f;
            }
        }
    }

    float m = -3.0e38f;
#pragma unroll
    for (int di = 0; di < KS; ++di)
#pragma unroll
        for (int kt = 0; kt < 2; ++kt)
#pragma unroll
            for (int r = 0; r < 4; ++r) m = fmaxf(m, s[di][kt][r]);
    m = fmaxf(m, __shfl_xor(m, 16, 64));
    m = fmaxf(m, __shfl_xor(m, 32, 64));
    float l = 0.f;
#pragma unroll
    for (int di = 0; di < KS; ++di)
#pragma unroll
        for (int kt = 0; kt < 2; ++kt)
#pragma unroll
            for (int r = 0; r < 4; ++r) {
                float p = __expf(s[di][kt][r] - m);
                s[di][kt][r] = p;
                l += p;
            }
    l += __shfl_xor(l, 16, 64);
    l += __shfl_xor(l, 32, 64);

    f32x4 O[4] = {};
    int addrA = ((2 * (g & 1)) * 16 + pix) * 4;
    int addrB = addrA + 64;
    bool kthi = (g >> 1) != 0;
#pragma unroll
    for (int di = 0; di < KS; ++di) {
        int iy = y + di - PAD;
        if (iy < 0 || iy >= 96) continue;
        unsigned int w0[2], w1[2];
#pragma unroll
        for (int kt = 0; kt < 2; ++kt) {
            asm("v_cvt_pk_bf16_f32 %0, %1, %2"
                : "=v"(w0[kt]) : "v"(s[di][kt][0]), "v"(s[di][kt][1]));
            asm("v_cvt_pk_bf16_f32 %0, %1, %2"
                : "=v"(w1[kt]) : "v"(s[di][kt][2]), "v"(s[di][kt][3]));
        }
        int a0 = __builtin_amdgcn_ds_bpermute(addrA, (int)w0[0]);
        int b0 = __builtin_amdgcn_ds_bpermute(addrA, (int)w0[1]);
        int a1 = __builtin_amdgcn_ds_bpermute(addrA, (int)w1[0]);
        int b1 = __builtin_amdgcn_ds_bpermute(addrA, (int)w1[1]);
        int a2 = __builtin_amdgcn_ds_bpermute(addrB, (int)w0[0]);
        int b2 = __builtin_amdgcn_ds_bpermute(addrB, (int)w0[1]);
        int a3 = __builtin_amdgcn_ds_bpermute(addrB, (int)w1[0]);
        int b3 = __builtin_amdgcn_ds_bpermute(addrB, (int)w1[1]);
        union { int u[4]; bf16x8 v; } pa;
        pa.u[0] = kthi ? b0 : a0;
        pa.u[1] = kthi ? b1 : a1;
        pa.u[2] = kthi ? b2 : a2;
        pa.u[3] = kthi ? b3 : a3;
#pragma unroll
        for (int dc = 0; dc < 4; ++dc) {
            long voff = ((long)((n * 64 + dc * 16 + pix) * 96 + iy)) * 96 + (W + g * 8);
            bf16x8 vf = *(const bf16x8*)(vt + voff);
            O[dc] = __builtin_amdgcn_mfma_f32_16x16x32_bf16(pa.v, vf, O[dc], 0, 0, 0);
        }
    }

    float linv = 1.0f / l;
    float linvj[4];
#pragma unroll
    for (int j = 0; j < 4; ++j)
        linvj[j] = __uint_as_float((unsigned)__builtin_amdgcn_ds_bpermute(
            (4 * g + j) * 4, (int)__float_as_uint(linv)));
#pragma unroll
    for (int dc = 0; dc < 4; ++dc)
#pragma unroll
        for (int j = 0; j < 4; ++j)
            sO[dc * 16 + pix][x0 + g * 4 + j] = O[dc][j] * linvj[j];
    __syncthreads();
    for (int i = tid; i < 1536; i += 384) {
        int d = i / 24, xq = i % 24;
        float4 v4 = { sO[d][xq * 4], sO[d][xq * 4 + 1],
                      sO[d][xq * 4 + 2], sO[d][xq * 4 + 3] };
        *(float4*)(out + ((size_t)(head * 8 + n) * 64 + d) * 9216
                   + y * 96 + xq * 4) = v4;
    }
}

// all 4 heads in one dispatch: head = blockIdx.x / 768
__global__ __launch_bounds__(384, 3) void na_mfma_all(
    const unsigned short* __restrict__ qkq, const unsigned short* __restrict__ vt,
    float* __restrict__ out)
{
    int head = blockIdx.x / 768;
    int bid = blockIdx.x % 768;
    switch (head) {
        case 0: na_body<3>(qkq, vt,               out, 0, bid); break;
        case 1: na_body<5>(qkq, vt + 4718592,     out, 1, bid); break;
        case 2: na_body<7>(qkq, vt + 2 * 4718592, out, 2, bid); break;
        default: na_body<9>(qkq, vt + 3 * 4718592, out, 3, bid); break;
    }
}

extern "C" void kernel_launch(void* const* d_in, const int* in_sizes, int n_in,
                              void* d_out, int out_size, void* d_ws, size_t ws_size,
                              hipStream_t stream) {
    const float* x  = (const float*)d_in[0];
    const float* w  = (const float*)d_in[1];
    const float* b  = (const float*)d_in[2];
    float* out = (float*)d_out;

    unsigned short* qkq  = (unsigned short*)d_ws;                       // 75497472 B (Q+K, stride 512)
    unsigned short* vt   = (unsigned short*)((char*)d_ws + 75497472);   // 37748736 B (V^T, 4 heads)
    unsigned short* xpad = (unsigned short*)((char*)d_ws + 113246208);  // 29503488 B
    unsigned short* bw   = (unsigned short*)((char*)d_ws + 142749696);  // 2654208 B

    hipMemsetAsync(xpad, 0, 29503488, stream);
    pack_x_kernel<<<NB * NH * 6, 256, 0, stream>>>(x, xpad);
    pack_w_kernel<<<COUT, 256, 0, stream>>>(w, bw);
    conv_gemm_kernel<<<864, 512, 0, stream>>>(xpad, bw, b, qkq, vt);

    na_mfma_all<<<4 * 768, 384, 0, stream>>>(qkq, vt, out);
}